// Round 5
// baseline (488.143 us; speedup 1.0000x reference)
//
#include <hip/hip_runtime.h>
#include <hip/hip_bf16.h>
#include <math.h>

// Problem dims (fixed)
#define BT    4096     // B*T rows
#define TSEQ  2048
#define DMODEL 1024
#define EDIM  2048
#define E2    4096     // 2*E
#define GG    16       // groups
#define NS    16       // state
#define DFF   4096
#define NCH   64       // scan chunks
#define CL    32       // chunk length (NCH*CL == TSEQ)

typedef __attribute__((ext_vector_type(8))) short short8_t;
typedef __attribute__((ext_vector_type(4))) float f32x4;

__device__ __forceinline__ void gload_lds16(const void* g, void* l) {
  __builtin_amdgcn_global_load_lds((const __attribute__((address_space(1))) void*)g,
                                   (__attribute__((address_space(3))) void*)l, 16, 0, 0);
}

// ---------------- RMSNorm (fp32 in -> bf16 out) ----------------
__global__ void rmsnorm_bf16(const float* __restrict__ x, const float* __restrict__ w,
                             __hip_bfloat16* __restrict__ out) {
  int row = blockIdx.x;
  const float* xr = x + (size_t)row * DMODEL;
  float ss = 0.f;
#pragma unroll
  for (int i = 0; i < 4; ++i) {
    float v = xr[threadIdx.x + i * 256];
    ss += v * v;
  }
#pragma unroll
  for (int off = 32; off; off >>= 1) ss += __shfl_down(ss, off, 64);
  __shared__ float wsum[4];
  int lane = threadIdx.x & 63, wid = threadIdx.x >> 6;
  if (lane == 0) wsum[wid] = ss;
  __syncthreads();
  __shared__ float s_rms;
  if (threadIdx.x == 0)
    s_rms = rsqrtf((wsum[0] + wsum[1] + wsum[2] + wsum[3]) * (1.0f / DMODEL) + 1e-6f);
  __syncthreads();
  float rms = s_rms;
  __hip_bfloat16* orow = out + (size_t)row * DMODEL;
#pragma unroll
  for (int i = 0; i < 4; ++i) {
    int c = threadIdx.x + i * 256;
    orow[c] = __float2bfloat16(xr[c] * rms * w[c]);
  }
}

// ---------------- transpose + fp32->bf16 convert: W[K,N] -> WT[N,K] ----------------
__global__ void transpose_to_bf16(const float* __restrict__ W, __hip_bfloat16* __restrict__ WT,
                                  int K, int N) {
  __shared__ float tile[32][33];
  int tx = threadIdx.x & 31, ty = threadIdx.x >> 5;  // 32 x 8
  int n0 = blockIdx.x * 32, k0 = blockIdx.y * 32;
#pragma unroll
  for (int i = 0; i < 4; ++i)
    tile[ty + i * 8][tx] = W[(size_t)(k0 + ty + i * 8) * N + n0 + tx];
  __syncthreads();
#pragma unroll
  for (int i = 0; i < 4; ++i)
    WT[(size_t)(n0 + ty + i * 8) * K + k0 + tx] = __float2bfloat16(tile[tx][ty + i * 8]);
}

// ================= 8-wave pipelined GEMM (T3+T4+T5, ring-3 LDS) =================
// C[M,N] = A[M,K] @ WT[N,K]^T (+res). BM=128, BN=256, BK=64. 512 thr = 8 waves
// (2 wm x 4 wn), per-wave 64x64 out (4x4 frags 16x16x32). Ring-3 LDS slots of
// 48KB (A 128x64, B 256x64 bf16): during tile t, stage tile t+2; tile-boundary
// wait is vmcnt(6) (t+2's 6 loads stay in flight) -- never a full drain.
// Raw s_barrier (no vmcnt drain), setprio around MFMA clusters.
// LDS swizzle: byte col ^ ((row&7)<<4) on BOTH stage-source and ds_read.
template <int OUT_BF16>
__global__ __launch_bounds__(512) void gemm_mfma8(
    const __hip_bfloat16* __restrict__ A, const __hip_bfloat16* __restrict__ WT,
    const float* __restrict__ res, void* __restrict__ Cout,
    int M, int N, int K, int nbx) {
  __shared__ char smem[3 * 49152];   // 144 KiB
  const int tid = threadIdx.x;
  const int lane = tid & 63, wid = tid >> 6;
  const int wm = wid >> 2, wn = wid & 3;
  const int lr = lane & 15, lq = lane >> 4;

  // XCD-aware bijective swizzle (gridDim.x % 8 == 0)
  int nwg = gridDim.x, q = nwg >> 3;
  int sw8 = (blockIdx.x & 7) * q + (blockIdx.x >> 3);
  int bx = sw8 % nbx, by = sw8 / nbx;
  int brow = by * 128, bcol = bx * 256;

  const char* Ab = (const char*)(A + (size_t)brow * K);
  const char* Bb = (const char*)(WT + (size_t)bcol * K);
  const size_t rowB = (size_t)K * 2;

  f32x4 acc[4][4];
#pragma unroll
  for (int m = 0; m < 4; ++m)
#pragma unroll
    for (int n = 0; n < 4; ++n) acc[m][n] = (f32x4){0.f, 0.f, 0.f, 0.f};

  // stage chunk i of A (i=0..1) / B (i=0..3) for K-tile t into ring slot
  auto stageA = [&](int slot, int t, int i) {
    int c = i * 512 + tid;                     // chunk 0..1023
    int r = c >> 3;                            // row 0..127
    int cb = ((c & 7) << 4) ^ ((r & 7) << 4);  // inverse-swizzled src col
    gload_lds16(Ab + (size_t)r * rowB + (size_t)t * 128 + cb,
                smem + slot * 49152 + c * 16);
  };
  auto stageB = [&](int slot, int t, int i) {
    int c = i * 512 + tid;                     // chunk 0..2047
    int r = c >> 3;                            // row 0..255
    int cb = ((c & 7) << 4) ^ ((r & 7) << 4);
    gload_lds16(Bb + (size_t)r * rowB + (size_t)t * 128 + cb,
                smem + slot * 49152 + 16384 + c * 16);
  };
  auto rdA = [&](int slot, int mf, int kkb) -> short8_t {
    int row = wm * 64 + mf * 16 + lr;
    int off = row * 128 + ((kkb + lq * 16) ^ ((row & 7) << 4));
    return *(const short8_t*)(smem + slot * 49152 + off);
  };
  auto rdB = [&](int slot, int nf, int kkb) -> short8_t {
    int row = wn * 64 + nf * 16 + lr;
    int off = row * 128 + ((kkb + lq * 16) ^ ((row & 7) << 4));
    return *(const short8_t*)(smem + slot * 49152 + 16384 + off);
  };

  const int nt = K >> 6;
  // prologue: stage tiles 0 and 1 (slots 0,1); wait for tile 0 only
  stageA(0, 0, 0); stageB(0, 0, 0); stageB(0, 0, 1);
  stageA(0, 0, 1); stageB(0, 0, 2); stageB(0, 0, 3);
  stageA(1, 1, 0); stageB(1, 1, 0); stageB(1, 1, 1);
  stageA(1, 1, 1); stageB(1, 1, 2); stageB(1, 1, 3);
  asm volatile("s_waitcnt vmcnt(6)" ::: "memory");
  __builtin_amdgcn_s_barrier();
  __builtin_amdgcn_sched_barrier(0);

  for (int t = 0; t < nt; ++t) {
    const int si = t % 3;
    const int s2 = (t + 2) % 3;
    const bool cs = (t + 2) < nt;

    // ---- phase 0 (kk bytes 0) ----
    if (cs) { stageA(s2, t + 2, 0); stageB(s2, t + 2, 0); stageB(s2, t + 2, 1); }
    {
      short8_t a0[4], b0[4];
#pragma unroll
      for (int mf = 0; mf < 4; ++mf) a0[mf] = rdA(si, mf, 0);
#pragma unroll
      for (int nf = 0; nf < 4; ++nf) b0[nf] = rdB(si, nf, 0);
      __builtin_amdgcn_s_setprio(1);
#pragma unroll
      for (int mf = 0; mf < 4; ++mf)
#pragma unroll
        for (int nf = 0; nf < 4; ++nf)
          acc[mf][nf] = __builtin_amdgcn_mfma_f32_16x16x32_bf16(a0[mf], b0[nf], acc[mf][nf], 0, 0, 0);
      __builtin_amdgcn_s_setprio(0);
    }
    __builtin_amdgcn_s_barrier();
    __builtin_amdgcn_sched_barrier(0);

    // ---- phase 1 (kk bytes 64) ----
    if (cs) { stageA(s2, t + 2, 1); stageB(s2, t + 2, 2); stageB(s2, t + 2, 3); }
    {
      short8_t a1[4], b1[4];
#pragma unroll
      for (int mf = 0; mf < 4; ++mf) a1[mf] = rdA(si, mf, 64);
#pragma unroll
      for (int nf = 0; nf < 4; ++nf) b1[nf] = rdB(si, nf, 64);
      __builtin_amdgcn_s_setprio(1);
#pragma unroll
      for (int mf = 0; mf < 4; ++mf)
#pragma unroll
        for (int nf = 0; nf < 4; ++nf)
          acc[mf][nf] = __builtin_amdgcn_mfma_f32_16x16x32_bf16(a1[mf], b1[nf], acc[mf][nf], 0, 0, 0);
      __builtin_amdgcn_s_setprio(0);
    }
    // tile boundary: counted wait (t+1's data landed; t+2's 6 loads in flight)
    if (cs)
      asm volatile("s_waitcnt vmcnt(6)" ::: "memory");
    else if (t + 1 < nt)
      asm volatile("s_waitcnt vmcnt(0)" ::: "memory");
    __builtin_amdgcn_s_barrier();
    __builtin_amdgcn_sched_barrier(0);
  }

  asm volatile("" ::: "memory");  // keep epilogue loads out of the loop
  // epilogue: C/D layout col=lane&15, row=(lane>>4)*4+reg
#pragma unroll
  for (int mf = 0; mf < 4; ++mf) {
    int row0 = brow + wm * 64 + mf * 16 + lq * 4;
#pragma unroll
    for (int nf = 0; nf < 4; ++nf) {
      int col = bcol + wn * 64 + nf * 16 + lr;
#pragma unroll
      for (int j = 0; j < 4; ++j) {
        size_t idx = (size_t)(row0 + j) * N + col;
        float o = acc[mf][nf][j];
        if (res) o += res[idx];
        if constexpr (OUT_BF16)
          ((__hip_bfloat16*)Cout)[idx] = __float2bfloat16(o);
        else
          ((float*)Cout)[idx] = o;
      }
    }
  }
}

// ---------------- bf16 MFMA GEMM, dbuf 2-phase (kept for small-N GEMMs) ----------------
template <int OUT_BF16>
__global__ __launch_bounds__(256) void gemm_mfma(
    const __hip_bfloat16* __restrict__ A, const __hip_bfloat16* __restrict__ WT,
    const float* __restrict__ res, void* __restrict__ Cout,
    int M, int N, int K, int nbx) {
  __shared__ __hip_bfloat16 As[2][128][64];
  __shared__ __hip_bfloat16 Bs[2][128][64];
  int tid = threadIdx.x;
  int lane = tid & 63, wid = tid >> 6;
  int wr = wid >> 1, wc = wid & 1;

  int nwg = gridDim.x;
  int q = nwg >> 3;
  int sw8 = (blockIdx.x & 7) * q + (blockIdx.x >> 3);
  int bx = sw8 % nbx, by = sw8 / nbx;
  int brow = by * 128, bcol = bx * 128;
  int lr = lane & 15, lq = lane >> 4;
  int sw = (lr & 7) << 4;

  f32x4 acc[4][4];
#pragma unroll
  for (int m = 0; m < 4; ++m)
#pragma unroll
    for (int n = 0; n < 4; ++n) acc[m][n] = (f32x4){0.f, 0.f, 0.f, 0.f};

  const char* Ab = (const char*)(A + (size_t)brow * K);
  const char* Bb = (const char*)(WT + (size_t)bcol * K);
  const size_t rowBytes = (size_t)K * 2;

  auto stage = [&](int buf, int t) {
    const size_t kb = (size_t)t * 128;
    char* asBase = (char*)&As[buf][0][0];
    char* bsBase = (char*)&Bs[buf][0][0];
#pragma unroll
    for (int i = 0; i < 4; ++i) {
      int blk = i * 4 + wid;
      int o16 = (blk << 6) + lane;
      int r = o16 >> 3;
      int cb = ((o16 & 7) << 4) ^ ((r & 7) << 4);
      gload_lds16(Ab + (size_t)r * rowBytes + kb + cb, asBase + (blk << 10));
    }
#pragma unroll
    for (int i = 0; i < 4; ++i) {
      int blk = i * 4 + wid;
      int o16 = (blk << 6) + lane;
      int r = o16 >> 3;
      int cb = ((o16 & 7) << 4) ^ ((r & 7) << 4);
      gload_lds16(Bb + (size_t)r * rowBytes + kb + cb, bsBase + (blk << 10));
    }
  };

  const int nt = K >> 6;
  stage(0, 0);
  __syncthreads();

  int cur = 0;
  for (int t = 0; t < nt; ++t) {
    if (t + 1 < nt) stage(cur ^ 1, t + 1);
#pragma unroll
    for (int kk6 = 0; kk6 < 2; ++kk6) {
      int cbs = ((kk6 << 6) + (lq << 4)) ^ sw;
      short8_t a[4], b[4];
#pragma unroll
      for (int m = 0; m < 4; ++m)
        a[m] = *(const short8_t*)((const char*)&As[cur][wr * 64 + m * 16 + lr][0] + cbs);
#pragma unroll
      for (int n = 0; n < 4; ++n)
        b[n] = *(const short8_t*)((const char*)&Bs[cur][wc * 64 + n * 16 + lr][0] + cbs);
#pragma unroll
      for (int m = 0; m < 4; ++m)
#pragma unroll
        for (int n = 0; n < 4; ++n)
          acc[m][n] = __builtin_amdgcn_mfma_f32_16x16x32_bf16(a[m], b[n], acc[m][n], 0, 0, 0);
    }
    __syncthreads();
    cur ^= 1;
  }

#pragma unroll
  for (int m = 0; m < 4; ++m) {
    int row0 = brow + wr * 64 + m * 16 + (lane >> 4) * 4;
#pragma unroll
    for (int n = 0; n < 4; ++n) {
      int col = bcol + wc * 64 + n * 16 + lr;
#pragma unroll
      for (int j = 0; j < 4; ++j) {
        size_t idx = (size_t)(row0 + j) * N + col;
        float o = acc[m][n][j];
        if (res) o += res[idx];
        if constexpr (OUT_BF16)
          ((__hip_bfloat16*)Cout)[idx] = __float2bfloat16(o);
        else
          ((float*)Cout)[idx] = o;
      }
    }
  }
}

// ---------------- depthwise causal conv (K=7), bf16 in/out ----------------
__global__ void dwconv_bf16(const __hip_bfloat16* __restrict__ uvb, const float* __restrict__ cw,
                            __hip_bfloat16* __restrict__ vout) {
  int e = blockIdx.x * 256 + threadIdx.x;   // 0..2047
  int bt = blockIdx.y;                       // 0..4095
  int t = bt & (TSEQ - 1);
  float w[7];
#pragma unroll
  for (int k = 0; k < 7; ++k) w[k] = cw[e * 7 + k];
  const __hip_bfloat16* col = uvb + (size_t)bt * E2 + EDIM + e;  // v half
  float acc = 0.f;
#pragma unroll
  for (int k = 0; k < 7; ++k) {
    int ts = t - 6 + k;
    if (ts >= 0) acc += w[k] * __bfloat162float(col[(ts - t) * (int)E2]);
  }
  vout[(size_t)bt * EDIM + e] = __float2bfloat16(acc);
}

// ---------------- dt projection + softplus (bf16 v, fp32 weights) ----------------
__global__ void dtproj_kernel(const __hip_bfloat16* __restrict__ v, const float* __restrict__ w,
                              const float* __restrict__ bias, float* __restrict__ dtout) {
  int row = blockIdx.x;
  const __hip_bfloat16* vr = v + (size_t)row * EDIM;
  float acc[GG] = {};
  for (int e = threadIdx.x; e < EDIM; e += 256) {
    float vv = __bfloat162float(vr[e]);
    const float* wr = w + (size_t)e * GG;
#pragma unroll
    for (int g = 0; g < GG; ++g) acc[g] = fmaf(vv, wr[g], acc[g]);
  }
#pragma unroll
  for (int g = 0; g < GG; ++g)
#pragma unroll
    for (int off = 32; off; off >>= 1) acc[g] += __shfl_down(acc[g], off, 64);
  __shared__ float red[4][GG];
  int lane = threadIdx.x & 63, wid = threadIdx.x >> 6;
  if (lane == 0) {
#pragma unroll
    for (int g = 0; g < GG; ++g) red[wid][g] = acc[g];
  }
  __syncthreads();
  if (threadIdx.x < GG) {
    float s = red[0][threadIdx.x] + red[1][threadIdx.x] + red[2][threadIdx.x] +
              red[3][threadIdx.x] + bias[threadIdx.x];
    dtout[(size_t)row * GG + threadIdx.x] = (s > 20.f) ? s : log1pf(expf(s));
  }
}

// ---------------- chunked selective scan (BC fused: [BT,512], Ct at +256) ----------------
__global__ void scan_phase1(const float* __restrict__ BC, const float* __restrict__ dt,
                            const float* __restrict__ A_log,
                            float* __restrict__ Pc, float* __restrict__ Sc) {
  int c = blockIdx.x, tid = threadIdx.x;
  int b = tid >> 8, g = (tid >> 4) & 15, n = tid & 15;
  float A = -expf(A_log[g * NS + n]);
  int t0 = c * CL;
  size_t bOff = (size_t)b * TSEQ * 512 + g * 16 + n;
  size_t dOff = (size_t)b * TSEQ * GG + g;
  float P = 1.f, S = 0.f;
  float Bv = BC[bOff + (size_t)t0 * 512], dv = dt[dOff + (size_t)t0 * GG];
  for (int t = t0; t < t0 + CL; ++t) {
    float nB = 0.f, nd = 0.f;
    if (t + 1 < t0 + CL) {
      nB = BC[bOff + (size_t)(t + 1) * 512];
      nd = dt[dOff + (size_t)(t + 1) * GG];
    }
    float a = expf(dv * A);
    S = a * S + dv * Bv;
    P *= a;
    Bv = nB; dv = nd;
  }
  Pc[c * 512 + tid] = P;
  Sc[c * 512 + tid] = S;
}

__global__ void scan_phase2(const float* __restrict__ Pc, const float* __restrict__ Sc,
                            float* __restrict__ Init) {
  int tid = threadIdx.x;
  float s = 0.f;
  for (int c = 0; c < NCH; ++c) {
    Init[c * 512 + tid] = s;
    s = Pc[c * 512 + tid] * s + Sc[c * 512 + tid];
  }
}

__global__ void scan_phase3(const float* __restrict__ BC, const float* __restrict__ dt,
                            const float* __restrict__ A_log, const float* __restrict__ Init,
                            float* __restrict__ y) {
  int c = blockIdx.x, tid = threadIdx.x;
  int b = tid >> 8, g = (tid >> 4) & 15, n = tid & 15;
  float A = -expf(A_log[g * NS + n]);
  int t0 = c * CL;
  size_t bOff = (size_t)b * TSEQ * 512 + g * 16 + n;
  size_t dOff = (size_t)b * TSEQ * GG + g;
  float state = Init[c * 512 + tid];
  float Bv = BC[bOff + (size_t)t0 * 512], Cv = BC[bOff + 256 + (size_t)t0 * 512],
        dv = dt[dOff + (size_t)t0 * GG];
  for (int t = t0; t < t0 + CL; ++t) {
    float nB = 0.f, nC = 0.f, nd = 0.f;
    if (t + 1 < t0 + CL) {
      size_t r = bOff + (size_t)(t + 1) * 512;
      nB = BC[r]; nC = BC[r + 256];
      nd = dt[dOff + (size_t)(t + 1) * GG];
    }
    float a = expf(dv * A);
    state = a * state + dv * Bv;
    float p = state * Cv;
#pragma unroll
    for (int off = 8; off; off >>= 1) p += __shfl_down(p, off, 16);
    if (n == 0) y[(size_t)(b * TSEQ + t) * GG + g] = p;
    Bv = nB; Cv = nC; dv = nd;
  }
}

// ---------------- gating: yg = sigmoid(u) * y_broadcast (bf16 out) ----------------
__global__ void gate_bf16(const __hip_bfloat16* __restrict__ uvb, const float* __restrict__ y,
                          __hip_bfloat16* __restrict__ yg) {
  size_t idx = (size_t)blockIdx.x * 256 + threadIdx.x;  // over BT*EDIM
  int bt = (int)(idx >> 11);
  int e = (int)(idx & (EDIM - 1));
  float u = __bfloat162float(uvb[(size_t)bt * E2 + e]);
  float yv = y[(size_t)bt * GG + (e >> 7)];
  yg[idx] = __float2bfloat16(yv / (1.f + expf(-u)));
}

// ---------------- swiglu on fused [t1|t3] buffer: ffb = silu(t1)*t3 ----------------
__global__ void swiglu_fused(const __hip_bfloat16* __restrict__ uv3,
                             __hip_bfloat16* __restrict__ ffb) {
  size_t idx = (size_t)blockIdx.x * 256 + threadIdx.x;  // over BT*DFF
  int bt = (int)(idx >> 12);
  int j = (int)(idx & (DFF - 1));
  const __hip_bfloat16* row = uv3 + (size_t)bt * 8192;
  float g = __bfloat162float(row[j]);
  float s = g / (1.f + expf(-g));
  ffb[idx] = __float2bfloat16(s * __bfloat162float(row[DFF + j]));
}

extern "C" void kernel_launch(void* const* d_in, const int* in_sizes, int n_in,
                              void* d_out, int out_size, void* d_ws, size_t ws_size,
                              hipStream_t stream) {
  (void)in_sizes; (void)n_in; (void)out_size; (void)ws_size;
  const float* x         = (const float*)d_in[0];
  const float* norm1_w   = (const float*)d_in[1];
  const float* in_proj_w = (const float*)d_in[2];
  const float* conv_w    = (const float*)d_in[3];
  const float* B_proj_w  = (const float*)d_in[4];
  const float* C_proj_w  = (const float*)d_in[5];
  const float* dt_proj_w = (const float*)d_in[6];
  const float* dt_proj_b = (const float*)d_in[7];
  const float* A_log     = (const float*)d_in[8];
  const float* out_proj_w= (const float*)d_in[9];
  const float* norm2_w   = (const float*)d_in[10];
  const float* w1        = (const float*)d_in[11];
  const float* w2        = (const float*)d_in[12];
  const float* w3        = (const float*)d_in[13];
  float* out = (float*)d_out;

  char* ws = (char*)d_ws;
  const size_t MB = 1024 * 1024;
  __hip_bfloat16* uvb  = (__hip_bfloat16*)(ws + 0);        // [4096,4096] 32MB; later ffb
  __hip_bfloat16* uv3b = (__hip_bfloat16*)(ws + 32 * MB);  // [4096,8192] 64MB (w13 out)
  __hip_bfloat16* vb   = (__hip_bfloat16*)(ws + 64 * MB);  // [4096,2048] 16MB
  __hip_bfloat16* yg   = (__hip_bfloat16*)(ws + 80 * MB);  // [4096,2048] 16MB
  __hip_bfloat16* ffb  = uvb;                              // 32MB overlay
  __hip_bfloat16* hb   = (__hip_bfloat16*)(ws + 96 * MB);  // [4096,1024] 8MB
  float* BCb  = (float*)(ws + 104 * MB);                   // [4096,512] 8MB
  float* dtb  = (float*)(ws + 112 * MB);                   // 256KB
  float* yb   = (float*)(ws + 112 * MB + 256 * 1024);      // 256KB
  float* Pc   = (float*)(ws + 113 * MB);                   // 128KB
  float* Sc   = (float*)(ws + 113 * MB + 128 * 1024);      // 128KB
  float* Init = (float*)(ws + 113 * MB + 256 * 1024);      // 128KB
  __hip_bfloat16* inT  = (__hip_bfloat16*)(ws + 114 * MB); // [4096,1024] 8MB
  __hip_bfloat16* BCT  = (__hip_bfloat16*)(ws + 122 * MB); // [512,2048] 2MB
  __hip_bfloat16* opT  = (__hip_bfloat16*)(ws + 124 * MB); // [1024,2048] 4MB
  __hip_bfloat16* w13T = (__hip_bfloat16*)(ws + 128 * MB); // [8192,1024] 16MB
  __hip_bfloat16* w2T  = (__hip_bfloat16*)(ws + 144 * MB); // [1024,4096] 8MB

  // 0) weight transpose+convert (W[K,N] -> WT[N,K] bf16)
  transpose_to_bf16<<<dim3(4096 / 32, 1024 / 32), 256, 0, stream>>>(in_proj_w, inT, 1024, 4096);
  transpose_to_bf16<<<dim3(256 / 32, 2048 / 32), 256, 0, stream>>>(B_proj_w, BCT, 2048, 256);
  transpose_to_bf16<<<dim3(256 / 32, 2048 / 32), 256, 0, stream>>>(C_proj_w, BCT + 256 * 2048, 2048, 256);
  transpose_to_bf16<<<dim3(1024 / 32, 2048 / 32), 256, 0, stream>>>(out_proj_w, opT, 2048, 1024);
  transpose_to_bf16<<<dim3(4096 / 32, 1024 / 32), 256, 0, stream>>>(w1, w13T, 1024, 4096);
  transpose_to_bf16<<<dim3(4096 / 32, 1024 / 32), 256, 0, stream>>>(w3, w13T + (size_t)4096 * 1024, 1024, 4096);
  transpose_to_bf16<<<dim3(1024 / 32, 4096 / 32), 256, 0, stream>>>(w2, w2T, 4096, 1024);

  // 1) hb = rmsnorm(x) in bf16
  rmsnorm_bf16<<<BT, 256, 0, stream>>>(x, norm1_w, hb);
  // 2) uvb = hb @ in_proj  [4096,4096]  (grid 32x16=512, nbx=16)
  gemm_mfma8<1><<<512, 512, 0, stream>>>(hb, inT, nullptr, uvb, BT, E2, DMODEL, 16);
  // 3) vb = causal dwconv(uvb[:, E:2E])
  dwconv_bf16<<<dim3(EDIM / 256, BT), 256, 0, stream>>>(uvb, conv_w, vb);
  // 4) BCb = vb @ [B_proj|C_proj]  (N=512, old kernel, 128 blocks)
  gemm_mfma<0><<<128, 256, 0, stream>>>(vb, BCT, nullptr, BCb, BT, 512, EDIM, 4);
  // 5) dtb = softplus(vb @ dt_proj + b)
  dtproj_kernel<<<BT, 256, 0, stream>>>(vb, dt_proj_w, dt_proj_b, dtb);
  // 6) chunked scan -> yb [BT, G]
  scan_phase1<<<NCH, 512, 0, stream>>>(BCb, dtb, A_log, Pc, Sc);
  scan_phase2<<<1, 512, 0, stream>>>(Pc, Sc, Init);
  scan_phase3<<<NCH, 512, 0, stream>>>(BCb, dtb, A_log, Init, yb);
  // 7) yg = sigmoid(u) * broadcast(y)
  gate_bf16<<<(BT * EDIM) / 256, 256, 0, stream>>>(uvb, yb, yg);
  // 8) out = yg @ out_proj + x  (grid 32x4=128, nbx=4)
  gemm_mfma8<0><<<128, 512, 0, stream>>>(yg, opT, x, out, BT, DMODEL, EDIM, 4);
  // 9) hb = rmsnorm(out)
  rmsnorm_bf16<<<BT, 256, 0, stream>>>(out, norm2_w, hb);
  // 10) uv3b = hb @ [w1|w3]  (grid 32x32=1024, nbx=32)
  gemm_mfma8<1><<<1024, 512, 0, stream>>>(hb, w13T, nullptr, uv3b, BT, 8192, DMODEL, 32);
  // 11) ffb = silu(t1)*t3 (bf16, overlays uvb)
  swiglu_fused<<<(BT * DFF) / 256, 256, 0, stream>>>(uv3b, ffb);
  // 12) out += ffb @ w2  (grid 32x4=128, nbx=4)
  gemm_mfma8<0><<<128, 512, 0, stream>>>(ffb, w2T, out, out, BT, DMODEL, DFF, 4);
}

// Round 6
// 448.148 us; speedup vs baseline: 1.0892x; 1.0892x over previous
//
#include <hip/hip_runtime.h>
#include <hip/hip_bf16.h>
#include <math.h>

// Problem dims (fixed)
#define BT    4096     // B*T rows
#define TSEQ  2048
#define DMODEL 1024
#define EDIM  2048
#define E2    4096     // 2*E
#define GG    16       // groups
#define NS    16       // state
#define DFF   4096
#define NCH   64       // scan chunks
#define CL    32       // chunk length (NCH*CL == TSEQ)

typedef __attribute__((ext_vector_type(8))) short short8_t;
typedef __attribute__((ext_vector_type(4))) float f32x4;

__device__ __forceinline__ void gload_lds16(const void* g, void* l) {
  __builtin_amdgcn_global_load_lds((const __attribute__((address_space(1))) void*)g,
                                   (__attribute__((address_space(3))) void*)l, 16, 0, 0);
}

// ---------------- RMSNorm (fp32 in -> bf16 out) ----------------
__global__ void rmsnorm_bf16(const float* __restrict__ x, const float* __restrict__ w,
                             __hip_bfloat16* __restrict__ out) {
  int row = blockIdx.x;
  const float* xr = x + (size_t)row * DMODEL;
  float ss = 0.f;
#pragma unroll
  for (int i = 0; i < 4; ++i) {
    float v = xr[threadIdx.x + i * 256];
    ss += v * v;
  }
#pragma unroll
  for (int off = 32; off; off >>= 1) ss += __shfl_down(ss, off, 64);
  __shared__ float wsum[4];
  int lane = threadIdx.x & 63, wid = threadIdx.x >> 6;
  if (lane == 0) wsum[wid] = ss;
  __syncthreads();
  __shared__ float s_rms;
  if (threadIdx.x == 0)
    s_rms = rsqrtf((wsum[0] + wsum[1] + wsum[2] + wsum[3]) * (1.0f / DMODEL) + 1e-6f);
  __syncthreads();
  float rms = s_rms;
  __hip_bfloat16* orow = out + (size_t)row * DMODEL;
#pragma unroll
  for (int i = 0; i < 4; ++i) {
    int c = threadIdx.x + i * 256;
    orow[c] = __float2bfloat16(xr[c] * rms * w[c]);
  }
}

// ---------------- transpose + fp32->bf16 convert: W[K,N] -> WT[N,K] ----------------
__global__ void transpose_to_bf16(const float* __restrict__ W, __hip_bfloat16* __restrict__ WT,
                                  int K, int N) {
  __shared__ float tile[32][33];
  int tx = threadIdx.x & 31, ty = threadIdx.x >> 5;  // 32 x 8
  int n0 = blockIdx.x * 32, k0 = blockIdx.y * 32;
#pragma unroll
  for (int i = 0; i < 4; ++i)
    tile[ty + i * 8][tx] = W[(size_t)(k0 + ty + i * 8) * N + n0 + tx];
  __syncthreads();
#pragma unroll
  for (int i = 0; i < 4; ++i)
    WT[(size_t)(n0 + ty + i * 8) * K + k0 + tx] = __float2bfloat16(tile[tx][ty + i * 8]);
}

// transpose with 16-col interleave remap: dest row' = 32*(n>>4) + (n&15) + off
// (off=0 for w1, off=16 for w3) -> w13T rows alternate w1/w3 16-col fragments.
__global__ void transpose_ilv16(const float* __restrict__ W, __hip_bfloat16* __restrict__ WT,
                                int K, int N, int off) {
  __shared__ float tile[32][33];
  int tx = threadIdx.x & 31, ty = threadIdx.x >> 5;
  int n0 = blockIdx.x * 32, k0 = blockIdx.y * 32;
#pragma unroll
  for (int i = 0; i < 4; ++i)
    tile[ty + i * 8][tx] = W[(size_t)(k0 + ty + i * 8) * N + n0 + tx];
  __syncthreads();
#pragma unroll
  for (int i = 0; i < 4; ++i) {
    int n = n0 + ty + i * 8;
    int rp = 32 * (n >> 4) + (n & 15) + off;
    WT[(size_t)rp * K + k0 + tx] = __float2bfloat16(tile[tx][ty + i * 8]);
  }
}

// ================= 8-wave pipelined GEMM (ring-3 LDS, counted vmcnt) =================
// C[M,N] = A[M,K] @ WT[N,K]^T. BM=128, BN=256, BK=64. 512 thr = 8 waves (2x4).
// OUT_MODE: 0 = fp32 out (+res), 1 = bf16 out, 2 = fused swiglu (w13T interleaved,
//   writes silu(even frag)*odd frag to bf16 [M, N/2]).
// Block mapping: col-stripe per XCD -- g = xcd*per + i; by = g%nby (fast), bx = g/nby.
// Each XCD keeps its B column-stripe L2-resident and streams each A-panel once.
template <int OUT_MODE>
__global__ __launch_bounds__(512) void gemm_mfma8(
    const __hip_bfloat16* __restrict__ A, const __hip_bfloat16* __restrict__ WT,
    const float* __restrict__ res, void* __restrict__ Cout,
    int M, int N, int K, int nby) {
  __shared__ char smem[3 * 49152];   // 144 KiB
  const int tid = threadIdx.x;
  const int lane = tid & 63, wid = tid >> 6;
  const int wm = wid >> 2, wn = wid & 3;
  const int lr = lane & 15, lq = lane >> 4;

  // col-stripe XCD mapping (gridDim.x % 8 == 0)
  int nwg = gridDim.x, per = nwg >> 3;
  int g = (blockIdx.x & 7) * per + (blockIdx.x >> 3);
  int by = g % nby, bx = g / nby;
  int brow = by * 128, bcol = bx * 256;

  const char* Ab = (const char*)(A + (size_t)brow * K);
  const char* Bb = (const char*)(WT + (size_t)bcol * K);
  const size_t rowB = (size_t)K * 2;

  f32x4 acc[4][4];
#pragma unroll
  for (int m = 0; m < 4; ++m)
#pragma unroll
    for (int n = 0; n < 4; ++n) acc[m][n] = (f32x4){0.f, 0.f, 0.f, 0.f};

  auto stageA = [&](int slot, int t, int i) {
    int c = i * 512 + tid;
    int r = c >> 3;
    int cb = ((c & 7) << 4) ^ ((r & 7) << 4);
    gload_lds16(Ab + (size_t)r * rowB + (size_t)t * 128 + cb,
                smem + slot * 49152 + c * 16);
  };
  auto stageB = [&](int slot, int t, int i) {
    int c = i * 512 + tid;
    int r = c >> 3;
    int cb = ((c & 7) << 4) ^ ((r & 7) << 4);
    gload_lds16(Bb + (size_t)r * rowB + (size_t)t * 128 + cb,
                smem + slot * 49152 + 16384 + c * 16);
  };
  auto rdA = [&](int slot, int mf, int kkb) -> short8_t {
    int row = wm * 64 + mf * 16 + lr;
    int off = row * 128 + ((kkb + lq * 16) ^ ((row & 7) << 4));
    return *(const short8_t*)(smem + slot * 49152 + off);
  };
  auto rdB = [&](int slot, int nf, int kkb) -> short8_t {
    int row = wn * 64 + nf * 16 + lr;
    int off = row * 128 + ((kkb + lq * 16) ^ ((row & 7) << 4));
    return *(const short8_t*)(smem + slot * 49152 + 16384 + off);
  };

  const int nt = K >> 6;
  // prologue: stage tiles 0 and 1 (slots 0,1); wait for tile 0 only
  stageA(0, 0, 0); stageB(0, 0, 0); stageB(0, 0, 1);
  stageA(0, 0, 1); stageB(0, 0, 2); stageB(0, 0, 3);
  stageA(1, 1, 0); stageB(1, 1, 0); stageB(1, 1, 1);
  stageA(1, 1, 1); stageB(1, 1, 2); stageB(1, 1, 3);
  asm volatile("s_waitcnt vmcnt(6)" ::: "memory");
  __builtin_amdgcn_s_barrier();
  __builtin_amdgcn_sched_barrier(0);

  for (int t = 0; t < nt; ++t) {
    const int si = t % 3;
    const int s2 = (t + 2) % 3;
    const bool cs = (t + 2) < nt;

    // ---- phase 0 ----
    if (cs) { stageA(s2, t + 2, 0); stageB(s2, t + 2, 0); stageB(s2, t + 2, 1); }
    {
      short8_t a0[4], b0[4];
#pragma unroll
      for (int mf = 0; mf < 4; ++mf) a0[mf] = rdA(si, mf, 0);
#pragma unroll
      for (int nf = 0; nf < 4; ++nf) b0[nf] = rdB(si, nf, 0);
      __builtin_amdgcn_s_setprio(1);
#pragma unroll
      for (int mf = 0; mf < 4; ++mf)
#pragma unroll
        for (int nf = 0; nf < 4; ++nf)
          acc[mf][nf] = __builtin_amdgcn_mfma_f32_16x16x32_bf16(a0[mf], b0[nf], acc[mf][nf], 0, 0, 0);
      __builtin_amdgcn_s_setprio(0);
    }
    __builtin_amdgcn_s_barrier();
    __builtin_amdgcn_sched_barrier(0);

    // ---- phase 1 ----
    if (cs) { stageA(s2, t + 2, 1); stageB(s2, t + 2, 2); stageB(s2, t + 2, 3); }
    {
      short8_t a1[4], b1[4];
#pragma unroll
      for (int mf = 0; mf < 4; ++mf) a1[mf] = rdA(si, mf, 64);
#pragma unroll
      for (int nf = 0; nf < 4; ++nf) b1[nf] = rdB(si, nf, 64);
      __builtin_amdgcn_s_setprio(1);
#pragma unroll
      for (int mf = 0; mf < 4; ++mf)
#pragma unroll
        for (int nf = 0; nf < 4; ++nf)
          acc[mf][nf] = __builtin_amdgcn_mfma_f32_16x16x32_bf16(a1[mf], b1[nf], acc[mf][nf], 0, 0, 0);
      __builtin_amdgcn_s_setprio(0);
    }
    // tile boundary: counted wait (t+1 landed; t+2's 6 loads stay in flight)
    if (cs)
      asm volatile("s_waitcnt vmcnt(6)" ::: "memory");
    else if (t + 1 < nt)
      asm volatile("s_waitcnt vmcnt(0)" ::: "memory");
    __builtin_amdgcn_s_barrier();
    __builtin_amdgcn_sched_barrier(0);
  }

  asm volatile("" ::: "memory");
  // epilogue: C/D layout col=lane&15, row=(lane>>4)*4+reg
  if constexpr (OUT_MODE == 2) {
    // fused swiglu: even frag = t1, odd frag = t3 (interleaved w13T)
    const int No = N >> 1;
#pragma unroll
    for (int mf = 0; mf < 4; ++mf) {
      int row0 = brow + wm * 64 + mf * 16 + lq * 4;
#pragma unroll
      for (int nfp = 0; nfp < 2; ++nfp) {
        int nf = nfp * 2;
        int col = (bcol >> 1) + wn * 32 + nfp * 16 + lr;
#pragma unroll
        for (int j = 0; j < 4; ++j) {
          float gg = acc[mf][nf][j];
          float s = gg / (1.f + expf(-gg));
          float o = s * acc[mf][nf + 1][j];
          ((__hip_bfloat16*)Cout)[(size_t)(row0 + j) * No + col] = __float2bfloat16(o);
        }
      }
    }
  } else {
#pragma unroll
    for (int mf = 0; mf < 4; ++mf) {
      int row0 = brow + wm * 64 + mf * 16 + lq * 4;
#pragma unroll
      for (int nf = 0; nf < 4; ++nf) {
        int col = bcol + wn * 64 + nf * 16 + lr;
#pragma unroll
        for (int j = 0; j < 4; ++j) {
          size_t idx = (size_t)(row0 + j) * N + col;
          float o = acc[mf][nf][j];
          if (res) o += res[idx];
          if constexpr (OUT_MODE == 1)
            ((__hip_bfloat16*)Cout)[idx] = __float2bfloat16(o);
          else
            ((float*)Cout)[idx] = o;
        }
      }
    }
  }
}

// ---------------- bf16 MFMA GEMM, dbuf 2-phase (small-N GEMMs) ----------------
template <int OUT_BF16>
__global__ __launch_bounds__(256) void gemm_mfma(
    const __hip_bfloat16* __restrict__ A, const __hip_bfloat16* __restrict__ WT,
    const float* __restrict__ res, void* __restrict__ Cout,
    int M, int N, int K, int nby) {
  __shared__ __hip_bfloat16 As[2][128][64];
  __shared__ __hip_bfloat16 Bs[2][128][64];
  int tid = threadIdx.x;
  int lane = tid & 63, wid = tid >> 6;
  int wr = wid >> 1, wc = wid & 1;

  int nwg = gridDim.x, per = nwg >> 3;
  int g = (blockIdx.x & 7) * per + (blockIdx.x >> 3);
  int by = g % nby, bx = g / nby;
  int brow = by * 128, bcol = bx * 128;
  int lr = lane & 15, lq = lane >> 4;
  int sw = (lr & 7) << 4;

  f32x4 acc[4][4];
#pragma unroll
  for (int m = 0; m < 4; ++m)
#pragma unroll
    for (int n = 0; n < 4; ++n) acc[m][n] = (f32x4){0.f, 0.f, 0.f, 0.f};

  const char* Ab = (const char*)(A + (size_t)brow * K);
  const char* Bb = (const char*)(WT + (size_t)bcol * K);
  const size_t rowBytes = (size_t)K * 2;

  auto stage = [&](int buf, int t) {
    const size_t kb = (size_t)t * 128;
    char* asBase = (char*)&As[buf][0][0];
    char* bsBase = (char*)&Bs[buf][0][0];
#pragma unroll
    for (int i = 0; i < 4; ++i) {
      int blk = i * 4 + wid;
      int o16 = (blk << 6) + lane;
      int r = o16 >> 3;
      int cb = ((o16 & 7) << 4) ^ ((r & 7) << 4);
      gload_lds16(Ab + (size_t)r * rowBytes + kb + cb, asBase + (blk << 10));
    }
#pragma unroll
    for (int i = 0; i < 4; ++i) {
      int blk = i * 4 + wid;
      int o16 = (blk << 6) + lane;
      int r = o16 >> 3;
      int cb = ((o16 & 7) << 4) ^ ((r & 7) << 4);
      gload_lds16(Bb + (size_t)r * rowBytes + kb + cb, bsBase + (blk << 10));
    }
  };

  const int nt = K >> 6;
  stage(0, 0);
  __syncthreads();

  int cur = 0;
  for (int t = 0; t < nt; ++t) {
    if (t + 1 < nt) stage(cur ^ 1, t + 1);
#pragma unroll
    for (int kk6 = 0; kk6 < 2; ++kk6) {
      int cbs = ((kk6 << 6) + (lq << 4)) ^ sw;
      short8_t a[4], b[4];
#pragma unroll
      for (int m = 0; m < 4; ++m)
        a[m] = *(const short8_t*)((const char*)&As[cur][wr * 64 + m * 16 + lr][0] + cbs);
#pragma unroll
      for (int n = 0; n < 4; ++n)
        b[n] = *(const short8_t*)((const char*)&Bs[cur][wc * 64 + n * 16 + lr][0] + cbs);
#pragma unroll
      for (int m = 0; m < 4; ++m)
#pragma unroll
        for (int n = 0; n < 4; ++n)
          acc[m][n] = __builtin_amdgcn_mfma_f32_16x16x32_bf16(a[m], b[n], acc[m][n], 0, 0, 0);
    }
    __syncthreads();
    cur ^= 1;
  }

#pragma unroll
  for (int m = 0; m < 4; ++m) {
    int row0 = brow + wr * 64 + m * 16 + (lane >> 4) * 4;
#pragma unroll
    for (int n = 0; n < 4; ++n) {
      int col = bcol + wc * 64 + n * 16 + lr;
#pragma unroll
      for (int j = 0; j < 4; ++j) {
        size_t idx = (size_t)(row0 + j) * N + col;
        float o = acc[m][n][j];
        if (res) o += res[idx];
        if constexpr (OUT_BF16)
          ((__hip_bfloat16*)Cout)[idx] = __float2bfloat16(o);
        else
          ((float*)Cout)[idx] = o;
      }
    }
  }
}

// ---------------- depthwise causal conv (K=7), bf16 in/out ----------------
__global__ void dwconv_bf16(const __hip_bfloat16* __restrict__ uvb, const float* __restrict__ cw,
                            __hip_bfloat16* __restrict__ vout) {
  int e = blockIdx.x * 256 + threadIdx.x;   // 0..2047
  int bt = blockIdx.y;                       // 0..4095
  int t = bt & (TSEQ - 1);
  float w[7];
#pragma unroll
  for (int k = 0; k < 7; ++k) w[k] = cw[e * 7 + k];
  const __hip_bfloat16* col = uvb + (size_t)bt * E2 + EDIM + e;  // v half
  float acc = 0.f;
#pragma unroll
  for (int k = 0; k < 7; ++k) {
    int ts = t - 6 + k;
    if (ts >= 0) acc += w[k] * __bfloat162float(col[(ts - t) * (int)E2]);
  }
  vout[(size_t)bt * EDIM + e] = __float2bfloat16(acc);
}

// ---------------- dt projection + softplus (bf16 v, fp32 weights) ----------------
__global__ void dtproj_kernel(const __hip_bfloat16* __restrict__ v, const float* __restrict__ w,
                              const float* __restrict__ bias, float* __restrict__ dtout) {
  int row = blockIdx.x;
  const __hip_bfloat16* vr = v + (size_t)row * EDIM;
  float acc[GG] = {};
  for (int e = threadIdx.x; e < EDIM; e += 256) {
    float vv = __bfloat162float(vr[e]);
    const float* wr = w + (size_t)e * GG;
#pragma unroll
    for (int g = 0; g < GG; ++g) acc[g] = fmaf(vv, wr[g], acc[g]);
  }
#pragma unroll
  for (int g = 0; g < GG; ++g)
#pragma unroll
    for (int off = 32; off; off >>= 1) acc[g] += __shfl_down(acc[g], off, 64);
  __shared__ float red[4][GG];
  int lane = threadIdx.x & 63, wid = threadIdx.x >> 6;
  if (lane == 0) {
#pragma unroll
    for (int g = 0; g < GG; ++g) red[wid][g] = acc[g];
  }
  __syncthreads();
  if (threadIdx.x < GG) {
    float s = red[0][threadIdx.x] + red[1][threadIdx.x] + red[2][threadIdx.x] +
              red[3][threadIdx.x] + bias[threadIdx.x];
    dtout[(size_t)row * GG + threadIdx.x] = (s > 20.f) ? s : log1pf(expf(s));
  }
}

// ---------------- chunked selective scan (BC fused: [BT,512], Ct at +256) ----------------
__global__ void scan_phase1(const float* __restrict__ BC, const float* __restrict__ dt,
                            const float* __restrict__ A_log,
                            float* __restrict__ Pc, float* __restrict__ Sc) {
  int c = blockIdx.x, tid = threadIdx.x;
  int b = tid >> 8, g = (tid >> 4) & 15, n = tid & 15;
  float A = -expf(A_log[g * NS + n]);
  int t0 = c * CL;
  size_t bOff = (size_t)b * TSEQ * 512 + g * 16 + n;
  size_t dOff = (size_t)b * TSEQ * GG + g;
  float P = 1.f, S = 0.f;
  float Bv = BC[bOff + (size_t)t0 * 512], dv = dt[dOff + (size_t)t0 * GG];
  for (int t = t0; t < t0 + CL; ++t) {
    float nB = 0.f, nd = 0.f;
    if (t + 1 < t0 + CL) {
      nB = BC[bOff + (size_t)(t + 1) * 512];
      nd = dt[dOff + (size_t)(t + 1) * GG];
    }
    float a = expf(dv * A);
    S = a * S + dv * Bv;
    P *= a;
    Bv = nB; dv = nd;
  }
  Pc[c * 512 + tid] = P;
  Sc[c * 512 + tid] = S;
}

__global__ void scan_phase2(const float* __restrict__ Pc, const float* __restrict__ Sc,
                            float* __restrict__ Init) {
  int tid = threadIdx.x;
  float s = 0.f;
  for (int c = 0; c < NCH; ++c) {
    Init[c * 512 + tid] = s;
    s = Pc[c * 512 + tid] * s + Sc[c * 512 + tid];
  }
}

__global__ void scan_phase3(const float* __restrict__ BC, const float* __restrict__ dt,
                            const float* __restrict__ A_log, const float* __restrict__ Init,
                            float* __restrict__ y) {
  int c = blockIdx.x, tid = threadIdx.x;
  int b = tid >> 8, g = (tid >> 4) & 15, n = tid & 15;
  float A = -expf(A_log[g * NS + n]);
  int t0 = c * CL;
  size_t bOff = (size_t)b * TSEQ * 512 + g * 16 + n;
  size_t dOff = (size_t)b * TSEQ * GG + g;
  float state = Init[c * 512 + tid];
  float Bv = BC[bOff + (size_t)t0 * 512], Cv = BC[bOff + 256 + (size_t)t0 * 512],
        dv = dt[dOff + (size_t)t0 * GG];
  for (int t = t0; t < t0 + CL; ++t) {
    float nB = 0.f, nC = 0.f, nd = 0.f;
    if (t + 1 < t0 + CL) {
      size_t r = bOff + (size_t)(t + 1) * 512;
      nB = BC[r]; nC = BC[r + 256];
      nd = dt[dOff + (size_t)(t + 1) * GG];
    }
    float a = expf(dv * A);
    state = a * state + dv * Bv;
    float p = state * Cv;
#pragma unroll
    for (int off = 8; off; off >>= 1) p += __shfl_down(p, off, 16);
    if (n == 0) y[(size_t)(b * TSEQ + t) * GG + g] = p;
    Bv = nB; Cv = nC; dv = nd;
  }
}

// ---------------- gating: yg = sigmoid(u) * y_broadcast (bf16 out) ----------------
__global__ void gate_bf16(const __hip_bfloat16* __restrict__ uvb, const float* __restrict__ y,
                          __hip_bfloat16* __restrict__ yg) {
  size_t idx = (size_t)blockIdx.x * 256 + threadIdx.x;  // over BT*EDIM
  int bt = (int)(idx >> 11);
  int e = (int)(idx & (EDIM - 1));
  float u = __bfloat162float(uvb[(size_t)bt * E2 + e]);
  float yv = y[(size_t)bt * GG + (e >> 7)];
  yg[idx] = __float2bfloat16(yv / (1.f + expf(-u)));
}

extern "C" void kernel_launch(void* const* d_in, const int* in_sizes, int n_in,
                              void* d_out, int out_size, void* d_ws, size_t ws_size,
                              hipStream_t stream) {
  (void)in_sizes; (void)n_in; (void)out_size; (void)ws_size;
  const float* x         = (const float*)d_in[0];
  const float* norm1_w   = (const float*)d_in[1];
  const float* in_proj_w = (const float*)d_in[2];
  const float* conv_w    = (const float*)d_in[3];
  const float* B_proj_w  = (const float*)d_in[4];
  const float* C_proj_w  = (const float*)d_in[5];
  const float* dt_proj_w = (const float*)d_in[6];
  const float* dt_proj_b = (const float*)d_in[7];
  const float* A_log     = (const float*)d_in[8];
  const float* out_proj_w= (const float*)d_in[9];
  const float* norm2_w   = (const float*)d_in[10];
  const float* w1        = (const float*)d_in[11];
  const float* w2        = (const float*)d_in[12];
  const float* w3        = (const float*)d_in[13];
  float* out = (float*)d_out;

  char* ws = (char*)d_ws;
  const size_t MB = 1024 * 1024;
  __hip_bfloat16* uvb  = (__hip_bfloat16*)(ws + 0);        // [4096,4096] 32MB; later ffb
  __hip_bfloat16* vb   = (__hip_bfloat16*)(ws + 64 * MB);  // [4096,2048] 16MB
  __hip_bfloat16* yg   = (__hip_bfloat16*)(ws + 80 * MB);  // [4096,2048] 16MB
  __hip_bfloat16* ffb  = uvb;                              // 32MB overlay (uvb dead)
  __hip_bfloat16* hb   = (__hip_bfloat16*)(ws + 96 * MB);  // [4096,1024] 8MB
  float* BCb  = (float*)(ws + 104 * MB);                   // [4096,512] 8MB
  float* dtb  = (float*)(ws + 112 * MB);                   // 256KB
  float* yb   = (float*)(ws + 112 * MB + 256 * 1024);      // 256KB
  float* Pc   = (float*)(ws + 113 * MB);                   // 128KB
  float* Sc   = (float*)(ws + 113 * MB + 128 * 1024);      // 128KB
  float* Init = (float*)(ws + 113 * MB + 256 * 1024);      // 128KB
  __hip_bfloat16* inT  = (__hip_bfloat16*)(ws + 114 * MB); // [4096,1024] 8MB
  __hip_bfloat16* BCT  = (__hip_bfloat16*)(ws + 122 * MB); // [512,2048] 2MB
  __hip_bfloat16* opT  = (__hip_bfloat16*)(ws + 124 * MB); // [1024,2048] 4MB
  __hip_bfloat16* w13T = (__hip_bfloat16*)(ws + 128 * MB); // [8192,1024] 16MB (interleaved)
  __hip_bfloat16* w2T  = (__hip_bfloat16*)(ws + 144 * MB); // [1024,4096] 8MB

  // 0) weight transpose+convert (W[K,N] -> WT[N,K] bf16)
  transpose_to_bf16<<<dim3(4096 / 32, 1024 / 32), 256, 0, stream>>>(in_proj_w, inT, 1024, 4096);
  transpose_to_bf16<<<dim3(256 / 32, 2048 / 32), 256, 0, stream>>>(B_proj_w, BCT, 2048, 256);
  transpose_to_bf16<<<dim3(256 / 32, 2048 / 32), 256, 0, stream>>>(C_proj_w, BCT + 256 * 2048, 2048, 256);
  transpose_to_bf16<<<dim3(1024 / 32, 2048 / 32), 256, 0, stream>>>(out_proj_w, opT, 2048, 1024);
  transpose_ilv16<<<dim3(4096 / 32, 1024 / 32), 256, 0, stream>>>(w1, w13T, 1024, 4096, 0);
  transpose_ilv16<<<dim3(4096 / 32, 1024 / 32), 256, 0, stream>>>(w3, w13T, 1024, 4096, 16);
  transpose_to_bf16<<<dim3(1024 / 32, 4096 / 32), 256, 0, stream>>>(w2, w2T, 4096, 1024);

  // 1) hb = rmsnorm(x) in bf16
  rmsnorm_bf16<<<BT, 256, 0, stream>>>(x, norm1_w, hb);
  // 2) uvb = hb @ in_proj  [4096,4096]  (512 blocks, col-stripe)
  gemm_mfma8<1><<<512, 512, 0, stream>>>(hb, inT, nullptr, uvb, BT, E2, DMODEL, 32);
  // 3) vb = causal dwconv(uvb[:, E:2E])
  dwconv_bf16<<<dim3(EDIM / 256, BT), 256, 0, stream>>>(uvb, conv_w, vb);
  // 4) BCb = vb @ [B_proj|C_proj]  (N=512, 2-phase, 128 blocks)
  gemm_mfma<0><<<128, 256, 0, stream>>>(vb, BCT, nullptr, BCb, BT, 512, EDIM, 32);
  // 5) dtb = softplus(vb @ dt_proj + b)
  dtproj_kernel<<<BT, 256, 0, stream>>>(vb, dt_proj_w, dt_proj_b, dtb);
  // 6) chunked scan -> yb [BT, G]
  scan_phase1<<<NCH, 512, 0, stream>>>(BCb, dtb, A_log, Pc, Sc);
  scan_phase2<<<1, 512, 0, stream>>>(Pc, Sc, Init);
  scan_phase3<<<NCH, 512, 0, stream>>>(BCb, dtb, A_log, Init, yb);
  // 7) yg = sigmoid(u) * broadcast(y)
  gate_bf16<<<(BT * EDIM) / 256, 256, 0, stream>>>(uvb, yb, yg);
  // 8) out = yg @ out_proj + x  (128 blocks)
  gemm_mfma8<0><<<128, 512, 0, stream>>>(yg, opT, x, out, BT, DMODEL, EDIM, 32);
  // 9) hb = rmsnorm(out)
  rmsnorm_bf16<<<BT, 256, 0, stream>>>(out, norm2_w, hb);
  // 10) ffb = swiglu(hb @ [w1|w3 interleaved])  (1024 blocks, fused epilogue)
  gemm_mfma8<2><<<1024, 512, 0, stream>>>(hb, w13T, nullptr, ffb, BT, 8192, DMODEL, 32);
  // 12) out += ffb @ w2  (128 blocks)
  gemm_mfma8<0><<<128, 512, 0, stream>>>(ffb, w2T, out, out, BT, DMODEL, DFF, 32);
}

// Round 7
// 435.697 us; speedup vs baseline: 1.1204x; 1.0286x over previous
//
#include <hip/hip_runtime.h>
#include <hip/hip_bf16.h>
#include <math.h>

// Problem dims (fixed)
#define BT    4096     // B*T rows
#define TSEQ  2048
#define DMODEL 1024
#define EDIM  2048
#define E2    4096     // 2*E
#define GG    16       // groups
#define NS    16       // state
#define DFF   4096
#define NCH   64       // scan chunks
#define CL    32       // chunk length (NCH*CL == TSEQ)

typedef __attribute__((ext_vector_type(8))) short short8_t;
typedef __attribute__((ext_vector_type(4))) float f32x4;

__device__ __forceinline__ void gload_lds16(const void* g, void* l) {
  __builtin_amdgcn_global_load_lds((const __attribute__((address_space(1))) void*)g,
                                   (__attribute__((address_space(3))) void*)l, 16, 0, 0);
}

// ---------------- RMSNorm (fp32 in -> bf16 out) ----------------
__global__ void rmsnorm_bf16(const float* __restrict__ x, const float* __restrict__ w,
                             __hip_bfloat16* __restrict__ out) {
  int row = blockIdx.x;
  const float* xr = x + (size_t)row * DMODEL;
  float ss = 0.f;
#pragma unroll
  for (int i = 0; i < 4; ++i) {
    float v = xr[threadIdx.x + i * 256];
    ss += v * v;
  }
#pragma unroll
  for (int off = 32; off; off >>= 1) ss += __shfl_down(ss, off, 64);
  __shared__ float wsum[4];
  int lane = threadIdx.x & 63, wid = threadIdx.x >> 6;
  if (lane == 0) wsum[wid] = ss;
  __syncthreads();
  __shared__ float s_rms;
  if (threadIdx.x == 0)
    s_rms = rsqrtf((wsum[0] + wsum[1] + wsum[2] + wsum[3]) * (1.0f / DMODEL) + 1e-6f);
  __syncthreads();
  float rms = s_rms;
  __hip_bfloat16* orow = out + (size_t)row * DMODEL;
#pragma unroll
  for (int i = 0; i < 4; ++i) {
    int c = threadIdx.x + i * 256;
    orow[c] = __float2bfloat16(xr[c] * rms * w[c]);
  }
}

// ---------------- transpose + fp32->bf16 convert: W[K,N] -> WT[N,K] ----------------
__global__ void transpose_to_bf16(const float* __restrict__ W, __hip_bfloat16* __restrict__ WT,
                                  int K, int N) {
  __shared__ float tile[32][33];
  int tx = threadIdx.x & 31, ty = threadIdx.x >> 5;  // 32 x 8
  int n0 = blockIdx.x * 32, k0 = blockIdx.y * 32;
#pragma unroll
  for (int i = 0; i < 4; ++i)
    tile[ty + i * 8][tx] = W[(size_t)(k0 + ty + i * 8) * N + n0 + tx];
  __syncthreads();
#pragma unroll
  for (int i = 0; i < 4; ++i)
    WT[(size_t)(n0 + ty + i * 8) * K + k0 + tx] = __float2bfloat16(tile[tx][ty + i * 8]);
}

// transpose with 16-col interleave remap: dest row' = 32*(n>>4) + (n&15) + off
// (off=0 for w1, off=16 for w3) -> w13T rows alternate w1/w3 16-col fragments.
__global__ void transpose_ilv16(const float* __restrict__ W, __hip_bfloat16* __restrict__ WT,
                                int K, int N, int off) {
  __shared__ float tile[32][33];
  int tx = threadIdx.x & 31, ty = threadIdx.x >> 5;
  int n0 = blockIdx.x * 32, k0 = blockIdx.y * 32;
#pragma unroll
  for (int i = 0; i < 4; ++i)
    tile[ty + i * 8][tx] = W[(size_t)(k0 + ty + i * 8) * N + n0 + tx];
  __syncthreads();
#pragma unroll
  for (int i = 0; i < 4; ++i) {
    int n = n0 + ty + i * 8;
    int rp = 32 * (n >> 4) + (n & 15) + off;
    WT[(size_t)rp * K + k0 + tx] = __float2bfloat16(tile[tx][ty + i * 8]);
  }
}

// ========= deep-pipelined GEMM: BK=32 sub-tiles, ring-6 LDS, counted vmcnt =========
// C[M,N] = A[M,K] @ WT[N,K]^T. BM=128, BN in {256,128}. Waves 2 x (BN/64),
// each wave 64x64 out (4x4 frags of 16x16x32). Slot = A[128][32] + B[BN][32]
// bf16 (8KB + BN*64B). Stage sub-tile t+5 during t; boundary waits vmcnt(4L)
// (L = loads/thread/sub-tile) so 4 sub-tiles stay in flight; 1 barrier/sub-tile.
// LDS swizzle (64B rows): 16B-slot s' = s ^ ((row>>1)&3) -> 2-way bank aliasing
// (free). Applied to BOTH global source col and ds_read offset (involution).
// OUT_MODE: 0 = fp32 out (+res), 1 = bf16 out, 2 = fused swiglu (interleaved WT,
// writes silu(even frag)*odd frag to bf16 [M, N/2]).
template <int OUT_MODE, int BN>
__global__ __launch_bounds__(BN == 256 ? 512 : 256) void gemm_pipe(
    const __hip_bfloat16* __restrict__ A, const __hip_bfloat16* __restrict__ WT,
    const float* __restrict__ res, void* __restrict__ Cout,
    int M, int N, int K, int nby) {
  constexpr int WN   = BN / 64;          // waves along N: 4 or 2
  constexpr int NTHR = 128 * WN;         // 512 or 256
  constexpr int SLOT = (128 + BN) * 64;  // bytes: 24576 or 16384
  constexpr int LA   = 512 / NTHR;       // A chunks/thread: 1 or 2
  constexpr int LB   = (BN * 4) / NTHR;  // B chunks/thread: 2
  constexpr int L    = LA + LB;          // 3 or 4
  __shared__ char smem[6 * SLOT];

  const int tid = threadIdx.x;
  const int lane = tid & 63, wid = tid >> 6;
  const int wm = wid / WN, wn = wid % WN;
  const int lr = lane & 15, lq = lane >> 4;

  // col-stripe XCD mapping (gridDim.x % 8 == 0)
  int nwg = gridDim.x, per = nwg >> 3;
  int g = (blockIdx.x & 7) * per + (blockIdx.x >> 3);
  int by = g % nby, bx = g / nby;
  int brow = by * 128, bcol = bx * BN;

  const char* Ab = (const char*)(A + (size_t)brow * K);
  const char* Bb = (const char*)(WT + (size_t)bcol * K);
  const size_t rowB = (size_t)K * 2;

  // hoisted per-thread staging offsets (global byte off rel. to Ab/Bb; LDS slot-rel)
  size_t gA[LA], gB[LB];
  int lA[LA], lB[LB];
#pragma unroll
  for (int i = 0; i < LA; ++i) {
    int c = i * NTHR + tid;            // 0..511
    int r = c >> 2, s = c & 3;
    gA[i] = (size_t)r * rowB + (size_t)(((s ^ ((r >> 1) & 3))) << 4);
    lA[i] = c * 16;
  }
#pragma unroll
  for (int i = 0; i < LB; ++i) {
    int c = i * NTHR + tid;            // 0..BN*4-1
    int r = c >> 2, s = c & 3;
    gB[i] = (size_t)r * rowB + (size_t)(((s ^ ((r >> 1) & 3))) << 4);
    lB[i] = 8192 + c * 16;
  }
  // hoisted ds_read offsets (slot-relative)
  int offA[4], offB[4];
#pragma unroll
  for (int mf = 0; mf < 4; ++mf) {
    int row = wm * 64 + mf * 16 + lr;
    offA[mf] = row * 64 + ((lq ^ ((row >> 1) & 3)) << 4);
  }
#pragma unroll
  for (int nf = 0; nf < 4; ++nf) {
    int row = wn * 64 + nf * 16 + lr;
    offB[nf] = 8192 + row * 64 + ((lq ^ ((row >> 1) & 3)) << 4);
  }

  f32x4 acc[4][4];
#pragma unroll
  for (int m = 0; m < 4; ++m)
#pragma unroll
    for (int n = 0; n < 4; ++n) acc[m][n] = (f32x4){0.f, 0.f, 0.f, 0.f};

  auto stage = [&](int t) {
    char* sb = smem + (t % 6) * SLOT;
    size_t ko = (size_t)t * 64;   // 32 cols * 2B
#pragma unroll
    for (int i = 0; i < LA; ++i) gload_lds16(Ab + gA[i] + ko, sb + lA[i]);
#pragma unroll
    for (int i = 0; i < LB; ++i) gload_lds16(Bb + gB[i] + ko, sb + lB[i]);
  };

  const int NT = K >> 5;
  // prologue: stage sub-tiles 0..4; wait for 0 (4 sub-tiles x L loads in flight)
#pragma unroll
  for (int p = 0; p < 5; ++p) stage(p);
  if constexpr (L == 3) asm volatile("s_waitcnt vmcnt(12)" ::: "memory");
  else                  asm volatile("s_waitcnt vmcnt(16)" ::: "memory");
  __builtin_amdgcn_s_barrier();
  __builtin_amdgcn_sched_barrier(0);

  for (int t = 0; t < NT; ++t) {
    if (t + 5 < NT) stage(t + 5);
    const char* sp = smem + (t % 6) * SLOT;
    short8_t a[4], b[4];
#pragma unroll
    for (int mf = 0; mf < 4; ++mf) a[mf] = *(const short8_t*)(sp + offA[mf]);
#pragma unroll
    for (int nf = 0; nf < 4; ++nf) b[nf] = *(const short8_t*)(sp + offB[nf]);
    __builtin_amdgcn_s_setprio(1);
#pragma unroll
    for (int mf = 0; mf < 4; ++mf)
#pragma unroll
      for (int nf = 0; nf < 4; ++nf)
        acc[mf][nf] = __builtin_amdgcn_mfma_f32_16x16x32_bf16(a[mf], b[nf], acc[mf][nf], 0, 0, 0);
    __builtin_amdgcn_s_setprio(0);

    // boundary: ensure sub-tile t+1 landed. Loads issued after t+1 = c sub-tiles.
    int c = NT - 2 - t;
    if (c >= 0) {
      if (c > 4) c = 4;
      if constexpr (L == 3) {
        switch (c) {
          case 4: asm volatile("s_waitcnt vmcnt(12)" ::: "memory"); break;
          case 3: asm volatile("s_waitcnt vmcnt(9)"  ::: "memory"); break;
          case 2: asm volatile("s_waitcnt vmcnt(6)"  ::: "memory"); break;
          case 1: asm volatile("s_waitcnt vmcnt(3)"  ::: "memory"); break;
          default: asm volatile("s_waitcnt vmcnt(0)" ::: "memory"); break;
        }
      } else {
        switch (c) {
          case 4: asm volatile("s_waitcnt vmcnt(16)" ::: "memory"); break;
          case 3: asm volatile("s_waitcnt vmcnt(12)" ::: "memory"); break;
          case 2: asm volatile("s_waitcnt vmcnt(8)"  ::: "memory"); break;
          case 1: asm volatile("s_waitcnt vmcnt(4)"  ::: "memory"); break;
          default: asm volatile("s_waitcnt vmcnt(0)" ::: "memory"); break;
        }
      }
      __builtin_amdgcn_s_barrier();
      __builtin_amdgcn_sched_barrier(0);
    }
  }

  asm volatile("" ::: "memory");
  // epilogue: C/D layout col=lane&15, row=(lane>>4)*4+reg
  if constexpr (OUT_MODE == 2) {
    const int No = N >> 1;
#pragma unroll
    for (int mf = 0; mf < 4; ++mf) {
      int row0 = brow + wm * 64 + mf * 16 + lq * 4;
#pragma unroll
      for (int nfp = 0; nfp < 2; ++nfp) {
        int nf = nfp * 2;
        int col = (bcol >> 1) + wn * 32 + nfp * 16 + lr;
#pragma unroll
        for (int j = 0; j < 4; ++j) {
          float gg = acc[mf][nf][j];
          float s = gg / (1.f + expf(-gg));
          float o = s * acc[mf][nf + 1][j];
          ((__hip_bfloat16*)Cout)[(size_t)(row0 + j) * No + col] = __float2bfloat16(o);
        }
      }
    }
  } else {
#pragma unroll
    for (int mf = 0; mf < 4; ++mf) {
      int row0 = brow + wm * 64 + mf * 16 + lq * 4;
#pragma unroll
      for (int nf = 0; nf < 4; ++nf) {
        int col = bcol + wn * 64 + nf * 16 + lr;
#pragma unroll
        for (int j = 0; j < 4; ++j) {
          size_t idx = (size_t)(row0 + j) * N + col;
          float o = acc[mf][nf][j];
          if (res) o += res[idx];
          if constexpr (OUT_MODE == 1)
            ((__hip_bfloat16*)Cout)[idx] = __float2bfloat16(o);
          else
            ((float*)Cout)[idx] = o;
        }
      }
    }
  }
}

// ---------------- depthwise causal conv (K=7), bf16 in/out ----------------
__global__ void dwconv_bf16(const __hip_bfloat16* __restrict__ uvb, const float* __restrict__ cw,
                            __hip_bfloat16* __restrict__ vout) {
  int e = blockIdx.x * 256 + threadIdx.x;   // 0..2047
  int bt = blockIdx.y;                       // 0..4095
  int t = bt & (TSEQ - 1);
  float w[7];
#pragma unroll
  for (int k = 0; k < 7; ++k) w[k] = cw[e * 7 + k];
  const __hip_bfloat16* col = uvb + (size_t)bt * E2 + EDIM + e;  // v half
  float acc = 0.f;
#pragma unroll
  for (int k = 0; k < 7; ++k) {
    int ts = t - 6 + k;
    if (ts >= 0) acc += w[k] * __bfloat162float(col[(ts - t) * (int)E2]);
  }
  vout[(size_t)bt * EDIM + e] = __float2bfloat16(acc);
}

// ---------------- dt projection + softplus (bf16 v, fp32 weights) ----------------
__global__ void dtproj_kernel(const __hip_bfloat16* __restrict__ v, const float* __restrict__ w,
                              const float* __restrict__ bias, float* __restrict__ dtout) {
  int row = blockIdx.x;
  const __hip_bfloat16* vr = v + (size_t)row * EDIM;
  float acc[GG] = {};
  for (int e = threadIdx.x; e < EDIM; e += 256) {
    float vv = __bfloat162float(vr[e]);
    const float* wr = w + (size_t)e * GG;
#pragma unroll
    for (int g = 0; g < GG; ++g) acc[g] = fmaf(vv, wr[g], acc[g]);
  }
#pragma unroll
  for (int g = 0; g < GG; ++g)
#pragma unroll
    for (int off = 32; off; off >>= 1) acc[g] += __shfl_down(acc[g], off, 64);
  __shared__ float red[4][GG];
  int lane = threadIdx.x & 63, wid = threadIdx.x >> 6;
  if (lane == 0) {
#pragma unroll
    for (int g = 0; g < GG; ++g) red[wid][g] = acc[g];
  }
  __syncthreads();
  if (threadIdx.x < GG) {
    float s = red[0][threadIdx.x] + red[1][threadIdx.x] + red[2][threadIdx.x] +
              red[3][threadIdx.x] + bias[threadIdx.x];
    dtout[(size_t)row * GG + threadIdx.x] = (s > 20.f) ? s : log1pf(expf(s));
  }
}

// ---------------- chunked selective scan (BC fused: [BT,512], Ct at +256) ----------------
__global__ void scan_phase1(const float* __restrict__ BC, const float* __restrict__ dt,
                            const float* __restrict__ A_log,
                            float* __restrict__ Pc, float* __restrict__ Sc) {
  int c = blockIdx.x, tid = threadIdx.x;
  int b = tid >> 8, g = (tid >> 4) & 15, n = tid & 15;
  float A = -expf(A_log[g * NS + n]);
  int t0 = c * CL;
  size_t bOff = (size_t)b * TSEQ * 512 + g * 16 + n;
  size_t dOff = (size_t)b * TSEQ * GG + g;
  float P = 1.f, S = 0.f;
  float Bv = BC[bOff + (size_t)t0 * 512], dv = dt[dOff + (size_t)t0 * GG];
  for (int t = t0; t < t0 + CL; ++t) {
    float nB = 0.f, nd = 0.f;
    if (t + 1 < t0 + CL) {
      nB = BC[bOff + (size_t)(t + 1) * 512];
      nd = dt[dOff + (size_t)(t + 1) * GG];
    }
    float a = expf(dv * A);
    S = a * S + dv * Bv;
    P *= a;
    Bv = nB; dv = nd;
  }
  Pc[c * 512 + tid] = P;
  Sc[c * 512 + tid] = S;
}

__global__ void scan_phase2(const float* __restrict__ Pc, const float* __restrict__ Sc,
                            float* __restrict__ Init) {
  int tid = threadIdx.x;
  float s = 0.f;
  for (int c = 0; c < NCH; ++c) {
    Init[c * 512 + tid] = s;
    s = Pc[c * 512 + tid] * s + Sc[c * 512 + tid];
  }
}

__global__ void scan_phase3(const float* __restrict__ BC, const float* __restrict__ dt,
                            const float* __restrict__ A_log, const float* __restrict__ Init,
                            float* __restrict__ y) {
  int c = blockIdx.x, tid = threadIdx.x;
  int b = tid >> 8, g = (tid >> 4) & 15, n = tid & 15;
  float A = -expf(A_log[g * NS + n]);
  int t0 = c * CL;
  size_t bOff = (size_t)b * TSEQ * 512 + g * 16 + n;
  size_t dOff = (size_t)b * TSEQ * GG + g;
  float state = Init[c * 512 + tid];
  float Bv = BC[bOff + (size_t)t0 * 512], Cv = BC[bOff + 256 + (size_t)t0 * 512],
        dv = dt[dOff + (size_t)t0 * GG];
  for (int t = t0; t < t0 + CL; ++t) {
    float nB = 0.f, nC = 0.f, nd = 0.f;
    if (t + 1 < t0 + CL) {
      size_t r = bOff + (size_t)(t + 1) * 512;
      nB = BC[r]; nC = BC[r + 256];
      nd = dt[dOff + (size_t)(t + 1) * GG];
    }
    float a = expf(dv * A);
    state = a * state + dv * Bv;
    float p = state * Cv;
#pragma unroll
    for (int off = 8; off; off >>= 1) p += __shfl_down(p, off, 16);
    if (n == 0) y[(size_t)(b * TSEQ + t) * GG + g] = p;
    Bv = nB; Cv = nC; dv = nd;
  }
}

// ---------------- gating: yg = sigmoid(u) * y_broadcast (bf16 out) ----------------
__global__ void gate_bf16(const __hip_bfloat16* __restrict__ uvb, const float* __restrict__ y,
                          __hip_bfloat16* __restrict__ yg) {
  size_t idx = (size_t)blockIdx.x * 256 + threadIdx.x;  // over BT*EDIM
  int bt = (int)(idx >> 11);
  int e = (int)(idx & (EDIM - 1));
  float u = __bfloat162float(uvb[(size_t)bt * E2 + e]);
  float yv = y[(size_t)bt * GG + (e >> 7)];
  yg[idx] = __float2bfloat16(yv / (1.f + expf(-u)));
}

extern "C" void kernel_launch(void* const* d_in, const int* in_sizes, int n_in,
                              void* d_out, int out_size, void* d_ws, size_t ws_size,
                              hipStream_t stream) {
  (void)in_sizes; (void)n_in; (void)out_size; (void)ws_size;
  const float* x         = (const float*)d_in[0];
  const float* norm1_w   = (const float*)d_in[1];
  const float* in_proj_w = (const float*)d_in[2];
  const float* conv_w    = (const float*)d_in[3];
  const float* B_proj_w  = (const float*)d_in[4];
  const float* C_proj_w  = (const float*)d_in[5];
  const float* dt_proj_w = (const float*)d_in[6];
  const float* dt_proj_b = (const float*)d_in[7];
  const float* A_log     = (const float*)d_in[8];
  const float* out_proj_w= (const float*)d_in[9];
  const float* norm2_w   = (const float*)d_in[10];
  const float* w1        = (const float*)d_in[11];
  const float* w2        = (const float*)d_in[12];
  const float* w3        = (const float*)d_in[13];
  float* out = (float*)d_out;

  char* ws = (char*)d_ws;
  const size_t MB = 1024 * 1024;
  __hip_bfloat16* uvb  = (__hip_bfloat16*)(ws + 0);        // [4096,4096] 32MB; later ffb
  __hip_bfloat16* vb   = (__hip_bfloat16*)(ws + 64 * MB);  // [4096,2048] 16MB
  __hip_bfloat16* yg   = (__hip_bfloat16*)(ws + 80 * MB);  // [4096,2048] 16MB
  __hip_bfloat16* ffb  = uvb;                              // 32MB overlay (uvb dead)
  __hip_bfloat16* hb   = (__hip_bfloat16*)(ws + 96 * MB);  // [4096,1024] 8MB
  float* BCb  = (float*)(ws + 104 * MB);                   // [4096,512] 8MB
  float* dtb  = (float*)(ws + 112 * MB);                   // 256KB
  float* yb   = (float*)(ws + 112 * MB + 256 * 1024);      // 256KB
  float* Pc   = (float*)(ws + 113 * MB);                   // 128KB
  float* Sc   = (float*)(ws + 113 * MB + 128 * 1024);      // 128KB
  float* Init = (float*)(ws + 113 * MB + 256 * 1024);      // 128KB
  __hip_bfloat16* inT  = (__hip_bfloat16*)(ws + 114 * MB); // [4096,1024] 8MB
  __hip_bfloat16* BCT  = (__hip_bfloat16*)(ws + 122 * MB); // [512,2048] 2MB
  __hip_bfloat16* opT  = (__hip_bfloat16*)(ws + 124 * MB); // [1024,2048] 4MB
  __hip_bfloat16* w13T = (__hip_bfloat16*)(ws + 128 * MB); // [8192,1024] 16MB (interleaved)
  __hip_bfloat16* w2T  = (__hip_bfloat16*)(ws + 144 * MB); // [1024,4096] 8MB

  // 0) weight transpose+convert (W[K,N] -> WT[N,K] bf16)
  transpose_to_bf16<<<dim3(4096 / 32, 1024 / 32), 256, 0, stream>>>(in_proj_w, inT, 1024, 4096);
  transpose_to_bf16<<<dim3(256 / 32, 2048 / 32), 256, 0, stream>>>(B_proj_w, BCT, 2048, 256);
  transpose_to_bf16<<<dim3(256 / 32, 2048 / 32), 256, 0, stream>>>(C_proj_w, BCT + 256 * 2048, 2048, 256);
  transpose_to_bf16<<<dim3(1024 / 32, 2048 / 32), 256, 0, stream>>>(out_proj_w, opT, 2048, 1024);
  transpose_ilv16<<<dim3(4096 / 32, 1024 / 32), 256, 0, stream>>>(w1, w13T, 1024, 4096, 0);
  transpose_ilv16<<<dim3(4096 / 32, 1024 / 32), 256, 0, stream>>>(w3, w13T, 1024, 4096, 16);
  transpose_to_bf16<<<dim3(1024 / 32, 4096 / 32), 256, 0, stream>>>(w2, w2T, 4096, 1024);

  // 1) hb = rmsnorm(x) in bf16
  rmsnorm_bf16<<<BT, 256, 0, stream>>>(x, norm1_w, hb);
  // 2) uvb = hb @ in_proj  [4096,4096]  (512 blocks, BN=256)
  gemm_pipe<1, 256><<<512, 512, 0, stream>>>(hb, inT, nullptr, uvb, BT, E2, DMODEL, 32);
  // 3) vb = causal dwconv(uvb[:, E:2E])
  dwconv_bf16<<<dim3(EDIM / 256, BT), 256, 0, stream>>>(uvb, conv_w, vb);
  // 4) BCb = vb @ [B_proj|C_proj]  (N=512, BN=128, 128 blocks)
  gemm_pipe<0, 128><<<128, 256, 0, stream>>>(vb, BCT, nullptr, BCb, BT, 512, EDIM, 32);
  // 5) dtb = softplus(vb @ dt_proj + b)
  dtproj_kernel<<<BT, 256, 0, stream>>>(vb, dt_proj_w, dt_proj_b, dtb);
  // 6) chunked scan -> yb [BT, G]
  scan_phase1<<<NCH, 512, 0, stream>>>(BCb, dtb, A_log, Pc, Sc);
  scan_phase2<<<1, 512, 0, stream>>>(Pc, Sc, Init);
  scan_phase3<<<NCH, 512, 0, stream>>>(BCb, dtb, A_log, Init, yb);
  // 7) yg = sigmoid(u) * broadcast(y)
  gate_bf16<<<(BT * EDIM) / 256, 256, 0, stream>>>(uvb, yb, yg);
  // 8) out = yg @ out_proj + x  (N=1024, BN=128, 256 blocks)
  gemm_pipe<0, 128><<<256, 256, 0, stream>>>(yg, opT, x, out, BT, DMODEL, EDIM, 32);
  // 9) hb = rmsnorm(out)
  rmsnorm_bf16<<<BT, 256, 0, stream>>>(out, norm2_w, hb);
  // 10) ffb = swiglu(hb @ [w1|w3 interleaved])  (1024 blocks, BN=256, fused)
  gemm_pipe<2, 256><<<1024, 512, 0, stream>>>(hb, w13T, nullptr, ffb, BT, 8192, DMODEL, 32);
  // 12) out += ffb @ w2  (N=1024, BN=128, 256 blocks)
  gemm_pipe<0, 128><<<256, 256, 0, stream>>>(ffb, w2T, out, out, BT, DMODEL, DFF, 32);
}

// Round 8
// 409.978 us; speedup vs baseline: 1.1907x; 1.0627x over previous
//
#include <hip/hip_runtime.h>
#include <hip/hip_bf16.h>
#include <math.h>

// Problem dims (fixed)
#define BT    4096     // B*T rows
#define TSEQ  2048
#define DMODEL 1024
#define EDIM  2048
#define E2    4096     // 2*E
#define GG    16       // groups
#define NS    16       // state
#define DFF   4096
#define NCH   64       // scan chunks
#define CL    32       // chunk length (NCH*CL == TSEQ)

typedef __attribute__((ext_vector_type(8))) short short8_t;
typedef __attribute__((ext_vector_type(4))) float f32x4;

__device__ __forceinline__ void gload_lds16(const void* g, void* l) {
  __builtin_amdgcn_global_load_lds((const __attribute__((address_space(1))) void*)g,
                                   (__attribute__((address_space(3))) void*)l, 16, 0, 0);
}

// ---------------- RMSNorm (fp32 in -> bf16 out) ----------------
__global__ void rmsnorm_bf16(const float* __restrict__ x, const float* __restrict__ w,
                             __hip_bfloat16* __restrict__ out) {
  int row = blockIdx.x;
  const float* xr = x + (size_t)row * DMODEL;
  float ss = 0.f;
#pragma unroll
  for (int i = 0; i < 4; ++i) {
    float v = xr[threadIdx.x + i * 256];
    ss += v * v;
  }
#pragma unroll
  for (int off = 32; off; off >>= 1) ss += __shfl_down(ss, off, 64);
  __shared__ float wsum[4];
  int lane = threadIdx.x & 63, wid = threadIdx.x >> 6;
  if (lane == 0) wsum[wid] = ss;
  __syncthreads();
  __shared__ float s_rms;
  if (threadIdx.x == 0)
    s_rms = rsqrtf((wsum[0] + wsum[1] + wsum[2] + wsum[3]) * (1.0f / DMODEL) + 1e-6f);
  __syncthreads();
  float rms = s_rms;
  __hip_bfloat16* orow = out + (size_t)row * DMODEL;
#pragma unroll
  for (int i = 0; i < 4; ++i) {
    int c = threadIdx.x + i * 256;
    orow[c] = __float2bfloat16(xr[c] * rms * w[c]);
  }
}

// ---------------- transpose + fp32->bf16 convert: W[K,N] -> WT[N,K] ----------------
__global__ void transpose_to_bf16(const float* __restrict__ W, __hip_bfloat16* __restrict__ WT,
                                  int K, int N) {
  __shared__ float tile[32][33];
  int tx = threadIdx.x & 31, ty = threadIdx.x >> 5;  // 32 x 8
  int n0 = blockIdx.x * 32, k0 = blockIdx.y * 32;
#pragma unroll
  for (int i = 0; i < 4; ++i)
    tile[ty + i * 8][tx] = W[(size_t)(k0 + ty + i * 8) * N + n0 + tx];
  __syncthreads();
#pragma unroll
  for (int i = 0; i < 4; ++i)
    WT[(size_t)(n0 + ty + i * 8) * K + k0 + tx] = __float2bfloat16(tile[tx][ty + i * 8]);
}

// transpose with 16-col interleave remap: dest row' = 32*(n>>4) + (n&15) + off
__global__ void transpose_ilv16(const float* __restrict__ W, __hip_bfloat16* __restrict__ WT,
                                int K, int N, int off) {
  __shared__ float tile[32][33];
  int tx = threadIdx.x & 31, ty = threadIdx.x >> 5;
  int n0 = blockIdx.x * 32, k0 = blockIdx.y * 32;
#pragma unroll
  for (int i = 0; i < 4; ++i)
    tile[ty + i * 8][tx] = W[(size_t)(k0 + ty + i * 8) * N + n0 + tx];
  __syncthreads();
#pragma unroll
  for (int i = 0; i < 4; ++i) {
    int n = n0 + ty + i * 8;
    int rp = 32 * (n >> 4) + (n & 15) + off;
    WT[(size_t)rp * K + k0 + tx] = __float2bfloat16(tile[tx][ty + i * 8]);
  }
}

// dt_proj_w [2048,16] -> rows 512..527 of BCT [640,2048]
__global__ void dtT_kernel(const float* __restrict__ dtW, __hip_bfloat16* __restrict__ BCT) {
  int idx = blockIdx.x * 256 + threadIdx.x;   // 0..32767
  int n = idx >> 11, k = idx & 2047;
  BCT[(size_t)(512 + n) * 2048 + k] = __float2bfloat16(dtW[(size_t)k * GG + n]);
}

// ========= pipelined GEMM: BK=32, ring-3 LDS, counted vmcnt, 2-3 blocks/CU =========
// C[M,N] = A[M,K] @ WT[N,K]^T. BM=128, BN in {256,128}. Waves 2 x (BN/64),
// per-wave 64x64 out (4x4 frags of 16x16x32). Slot = A[128][32] + B[BN][32] bf16
// (24KB / 16KB); ring-3 = 72KB / 48KB -> 2-3 blocks per CU so stalls overlap.
// Stage sub-tile t+2 during t; boundary wait vmcnt(L) (t+2's loads in flight).
// LDS swizzle (64B rows): 16B-slot s' = s ^ ((row>>1)&3), on BOTH source & read.
// XCD mapping: 4x(bxl) 2D chunks per XCD (A-window+B-stripe fit 4MB L2);
// falls back to col-stripe when per-XCD count isn't 4-chunkable.
// OUT_MODE: 0 = fp32 out (+res, store-guarded col<nstore), 1 = bf16 out,
//           2 = fused swiglu (interleaved WT; silu(even)*odd -> bf16 [M,N/2]).
template <int OUT_MODE, int BN>
__global__ __launch_bounds__(BN == 256 ? 512 : 256) void gemm_pipe(
    const __hip_bfloat16* __restrict__ A, const __hip_bfloat16* __restrict__ WT,
    const float* __restrict__ res, void* __restrict__ Cout,
    int M, int N, int K, int nby, int nstore) {
  constexpr int WN   = BN / 64;          // waves along N: 4 or 2
  constexpr int NTHR = 128 * WN;         // 512 or 256
  constexpr int SLOT = (128 + BN) * 64;  // 24576 or 16384 bytes
  constexpr int LA   = 512 / NTHR;       // 1 or 2
  constexpr int LB   = (BN * 4) / NTHR;  // 2
  constexpr int L    = LA + LB;          // 3 or 4
  __shared__ char smem[3 * SLOT];

  const int tid = threadIdx.x;
  const int lane = tid & 63, wid = tid >> 6;
  const int wm = wid / WN, wn = wid % WN;
  const int lr = lane & 15, lq = lane >> 4;

  // XCD mapping
  int nwg = gridDim.x, per = nwg >> 3;
  int xcd = blockIdx.x & 7, local = blockIdx.x >> 3;
  int by, bx;
  int bxl = per / nby;
  if (bxl >= 1 && bxl * nby == per) {
    int cw = 4 * bxl;
    int chunk = local / cw, wi = local % cw;
    by = chunk * 4 + (wi & 3);
    bx = xcd * bxl + (wi >> 2);
  } else {
    int g = xcd * per + local;
    by = g % nby; bx = g / nby;
  }
  int brow = by * 128, bcol = bx * BN;

  const char* Ab = (const char*)(A + (size_t)brow * K);
  const char* Bb = (const char*)(WT + (size_t)bcol * K);
  const size_t rowB = (size_t)K * 2;

  // hoisted per-thread staging offsets
  size_t gA[LA], gB[LB];
  int lA[LA], lB[LB];
#pragma unroll
  for (int i = 0; i < LA; ++i) {
    int c = i * NTHR + tid;            // 0..511
    int r = c >> 2, s = c & 3;
    gA[i] = (size_t)r * rowB + (size_t)((s ^ ((r >> 1) & 3)) << 4);
    lA[i] = c * 16;
  }
#pragma unroll
  for (int i = 0; i < LB; ++i) {
    int c = i * NTHR + tid;            // 0..BN*4-1
    int r = c >> 2, s = c & 3;
    gB[i] = (size_t)r * rowB + (size_t)((s ^ ((r >> 1) & 3)) << 4);
    lB[i] = 8192 + c * 16;
  }
  // hoisted ds_read offsets (slot-relative)
  int offA[4], offB[4];
#pragma unroll
  for (int mf = 0; mf < 4; ++mf) {
    int row = wm * 64 + mf * 16 + lr;
    offA[mf] = row * 64 + ((lq ^ ((row >> 1) & 3)) << 4);
  }
#pragma unroll
  for (int nf = 0; nf < 4; ++nf) {
    int row = wn * 64 + nf * 16 + lr;
    offB[nf] = 8192 + row * 64 + ((lq ^ ((row >> 1) & 3)) << 4);
  }

  f32x4 acc[4][4];
#pragma unroll
  for (int m = 0; m < 4; ++m)
#pragma unroll
    for (int n = 0; n < 4; ++n) acc[m][n] = (f32x4){0.f, 0.f, 0.f, 0.f};

  auto stage = [&](int slotOff, int t) {
    char* sb = smem + slotOff;
    size_t ko = (size_t)t * 64;   // 32 cols * 2B
#pragma unroll
    for (int i = 0; i < LA; ++i) gload_lds16(Ab + gA[i] + ko, sb + lA[i]);
#pragma unroll
    for (int i = 0; i < LB; ++i) gload_lds16(Bb + gB[i] + ko, sb + lB[i]);
  };

  const int NT = K >> 5;
  int sl0 = 0, sl1 = SLOT, sl2 = 2 * SLOT;  // slots for t, t+1, t+2
  stage(sl0, 0);
  stage(sl1, 1);
  if constexpr (L == 3) asm volatile("s_waitcnt vmcnt(3)" ::: "memory");
  else                  asm volatile("s_waitcnt vmcnt(4)" ::: "memory");
  __builtin_amdgcn_s_barrier();
  __builtin_amdgcn_sched_barrier(0);

  for (int t = 0; t < NT; ++t) {
    if (t + 2 < NT) stage(sl2, t + 2);
    const char* sp = smem + sl0;
    short8_t a[4], b[4];
#pragma unroll
    for (int mf = 0; mf < 4; ++mf) a[mf] = *(const short8_t*)(sp + offA[mf]);
#pragma unroll
    for (int nf = 0; nf < 4; ++nf) b[nf] = *(const short8_t*)(sp + offB[nf]);
    __builtin_amdgcn_s_setprio(1);
#pragma unroll
    for (int mf = 0; mf < 4; ++mf)
#pragma unroll
      for (int nf = 0; nf < 4; ++nf)
        acc[mf][nf] = __builtin_amdgcn_mfma_f32_16x16x32_bf16(a[mf], b[nf], acc[mf][nf], 0, 0, 0);
    __builtin_amdgcn_s_setprio(0);

    if (t + 1 < NT) {
      if (t + 2 < NT) {
        if constexpr (L == 3) asm volatile("s_waitcnt vmcnt(3)" ::: "memory");
        else                  asm volatile("s_waitcnt vmcnt(4)" ::: "memory");
      } else {
        asm volatile("s_waitcnt vmcnt(0)" ::: "memory");
      }
      __builtin_amdgcn_s_barrier();
      __builtin_amdgcn_sched_barrier(0);
    }
    int tmp = sl0; sl0 = sl1; sl1 = sl2; sl2 = tmp;
  }

  asm volatile("" ::: "memory");
  // epilogue: C/D layout col=lane&15, row=(lane>>4)*4+reg
  if constexpr (OUT_MODE == 2) {
    const int No = N >> 1;
#pragma unroll
    for (int mf = 0; mf < 4; ++mf) {
      int row0 = brow + wm * 64 + mf * 16 + lq * 4;
#pragma unroll
      for (int nfp = 0; nfp < 2; ++nfp) {
        int nf = nfp * 2;
        int col = (bcol >> 1) + wn * 32 + nfp * 16 + lr;
#pragma unroll
        for (int j = 0; j < 4; ++j) {
          float gg = acc[mf][nf][j];
          float s = gg / (1.f + expf(-gg));
          float o = s * acc[mf][nf + 1][j];
          ((__hip_bfloat16*)Cout)[(size_t)(row0 + j) * No + col] = __float2bfloat16(o);
        }
      }
    }
  } else if constexpr (OUT_MODE == 1) {
#pragma unroll
    for (int mf = 0; mf < 4; ++mf) {
      int row0 = brow + wm * 64 + mf * 16 + lq * 4;
#pragma unroll
      for (int nf = 0; nf < 4; ++nf) {
        int col = bcol + wn * 64 + nf * 16 + lr;
#pragma unroll
        for (int j = 0; j < 4; ++j)
          ((__hip_bfloat16*)Cout)[(size_t)(row0 + j) * N + col] =
              __float2bfloat16(acc[mf][nf][j]);
      }
    }
  } else {
#pragma unroll
    for (int mf = 0; mf < 4; ++mf) {
      int row0 = brow + wm * 64 + mf * 16 + lq * 4;
#pragma unroll
      for (int nf = 0; nf < 4; ++nf) {
        int col = bcol + wn * 64 + nf * 16 + lr;
        if (col < nstore) {
#pragma unroll
          for (int j = 0; j < 4; ++j) {
            size_t idx = (size_t)(row0 + j) * N + col;
            float o = acc[mf][nf][j];
            if (res) o += res[idx];
            ((float*)Cout)[idx] = o;
          }
        }
      }
    }
  }
}

// ---------------- depthwise causal conv (K=7), bf16 in/out ----------------
__global__ void dwconv_bf16(const __hip_bfloat16* __restrict__ uvb, const float* __restrict__ cw,
                            __hip_bfloat16* __restrict__ vout) {
  int e = blockIdx.x * 256 + threadIdx.x;   // 0..2047
  int bt = blockIdx.y;                       // 0..4095
  int t = bt & (TSEQ - 1);
  float w[7];
#pragma unroll
  for (int k = 0; k < 7; ++k) w[k] = cw[e * 7 + k];
  const __hip_bfloat16* col = uvb + (size_t)bt * E2 + EDIM + e;  // v half
  float acc = 0.f;
#pragma unroll
  for (int k = 0; k < 7; ++k) {
    int ts = t - 6 + k;
    if (ts >= 0) acc += w[k] * __bfloat162float(col[(ts - t) * (int)E2]);
  }
  vout[(size_t)bt * EDIM + e] = __float2bfloat16(acc);
}

// ---------------- chunked selective scan over BCD [BT,640] (B|C|dt) ----------------
__device__ __forceinline__ float softplus_f(float s) {
  return (s > 20.f) ? s : log1pf(expf(s));
}

__global__ void scan_phase1(const float* __restrict__ BCD, const float* __restrict__ A_log,
                            const float* __restrict__ dt_bias,
                            float* __restrict__ Pc, float* __restrict__ Sc) {
  int c = blockIdx.x, tid = threadIdx.x;
  int b = tid >> 8, g = (tid >> 4) & 15, n = tid & 15;
  float A = -expf(A_log[g * NS + n]);
  float bias = dt_bias[g];
  int t0 = c * CL;
  size_t base = (size_t)(b * TSEQ + t0) * 640;
  const float* pB = BCD + base + g * 16 + n;
  const float* pd = BCD + base + 512 + g;
  float P = 1.f, S = 0.f;
  float Bv = pB[0], rd = pd[0];
  for (int t = 0; t < CL; ++t) {
    float nB = 0.f, nd = 0.f;
    if (t + 1 < CL) { nB = pB[(size_t)(t + 1) * 640]; nd = pd[(size_t)(t + 1) * 640]; }
    float dv = softplus_f(rd + bias);
    float a = expf(dv * A);
    S = a * S + dv * Bv;
    P *= a;
    Bv = nB; rd = nd;
  }
  Pc[c * 512 + tid] = P;
  Sc[c * 512 + tid] = S;
}

__global__ void scan_phase2(const float* __restrict__ Pc, const float* __restrict__ Sc,
                            float* __restrict__ Init) {
  int tid = threadIdx.x;
  float s = 0.f;
  for (int c = 0; c < NCH; ++c) {
    Init[c * 512 + tid] = s;
    s = Pc[c * 512 + tid] * s + Sc[c * 512 + tid];
  }
}

// phase3 with fused gating: y -> all lanes via shfl_xor; yg = sigmoid(u)*y (bf16)
__global__ void scan_phase3(const float* __restrict__ BCD, const float* __restrict__ A_log,
                            const float* __restrict__ dt_bias, const float* __restrict__ Init,
                            const __hip_bfloat16* __restrict__ uvb,
                            __hip_bfloat16* __restrict__ yg) {
  int c = blockIdx.x, tid = threadIdx.x;
  int b = tid >> 8, g = (tid >> 4) & 15, n = tid & 15;
  float A = -expf(A_log[g * NS + n]);
  float bias = dt_bias[g];
  int t0 = c * CL;
  size_t base = (size_t)(b * TSEQ + t0) * 640;
  const float* pB = BCD + base + g * 16 + n;
  const float* pC = pB + 256;
  const float* pd = BCD + base + 512 + g;
  float state = Init[c * 512 + tid];
  float Bv = pB[0], Cv = pC[0], rd = pd[0];
  for (int t = 0; t < CL; ++t) {
    float nB = 0.f, nC = 0.f, nd = 0.f;
    if (t + 1 < CL) {
      size_t r = (size_t)(t + 1) * 640;
      nB = pB[r]; nC = pC[r]; nd = pd[r];
    }
    float dv = softplus_f(rd + bias);
    float a = expf(dv * A);
    state = a * state + dv * Bv;
    float p = state * Cv;
#pragma unroll
    for (int off = 8; off; off >>= 1) p += __shfl_xor(p, off, 16);
    // fused gate: 8 channels per lane
    int bt = b * TSEQ + t0 + t;
    union { short8_t v; __hip_bfloat16 h[8]; } U, O;
    U.v = *(const short8_t*)(uvb + (size_t)bt * E2 + g * 128 + n * 8);
#pragma unroll
    for (int j = 0; j < 8; ++j) {
      float u = __bfloat162float(U.h[j]);
      O.h[j] = __float2bfloat16(p / (1.f + expf(-u)));
    }
    *(short8_t*)(yg + (size_t)bt * EDIM + g * 128 + n * 8) = O.v;
    Bv = nB; Cv = nC; rd = nd;
  }
}

extern "C" void kernel_launch(void* const* d_in, const int* in_sizes, int n_in,
                              void* d_out, int out_size, void* d_ws, size_t ws_size,
                              hipStream_t stream) {
  (void)in_sizes; (void)n_in; (void)out_size; (void)ws_size;
  const float* x         = (const float*)d_in[0];
  const float* norm1_w   = (const float*)d_in[1];
  const float* in_proj_w = (const float*)d_in[2];
  const float* conv_w    = (const float*)d_in[3];
  const float* B_proj_w  = (const float*)d_in[4];
  const float* C_proj_w  = (const float*)d_in[5];
  const float* dt_proj_w = (const float*)d_in[6];
  const float* dt_proj_b = (const float*)d_in[7];
  const float* A_log     = (const float*)d_in[8];
  const float* out_proj_w= (const float*)d_in[9];
  const float* norm2_w   = (const float*)d_in[10];
  const float* w1        = (const float*)d_in[11];
  const float* w2        = (const float*)d_in[12];
  const float* w3        = (const float*)d_in[13];
  float* out = (float*)d_out;

  char* ws = (char*)d_ws;
  const size_t MB = 1024 * 1024;
  __hip_bfloat16* uvb  = (__hip_bfloat16*)(ws + 0);        // [4096,4096] 32MB; later ffb
  __hip_bfloat16* vb   = (__hip_bfloat16*)(ws + 64 * MB);  // [4096,2048] 16MB
  __hip_bfloat16* yg   = (__hip_bfloat16*)(ws + 80 * MB);  // [4096,2048] 16MB
  __hip_bfloat16* ffb  = uvb;                              // 32MB overlay (uvb dead)
  __hip_bfloat16* hb   = (__hip_bfloat16*)(ws + 96 * MB);  // [4096,1024] 8MB
  float* BCD  = (float*)(ws + 104 * MB);                   // [4096,640] fp32 = 10MB
  float* Pc   = (float*)(ws + 114 * MB);                   // 128KB
  float* Sc   = (float*)(ws + 114 * MB + 128 * 1024);      // 128KB
  float* Init = (float*)(ws + 114 * MB + 256 * 1024);      // 128KB
  __hip_bfloat16* inT  = (__hip_bfloat16*)(ws + 115 * MB); // [4096,1024] 8MB
  __hip_bfloat16* BCT  = (__hip_bfloat16*)(ws + 123 * MB); // [640,2048] 2.5MB
  __hip_bfloat16* opT  = (__hip_bfloat16*)(ws + 126 * MB); // [1024,2048] 4MB
  __hip_bfloat16* w13T = (__hip_bfloat16*)(ws + 130 * MB); // [8192,1024] 16MB (ilv)
  __hip_bfloat16* w2T  = (__hip_bfloat16*)(ws + 146 * MB); // [1024,4096] 8MB

  // 0) weight transpose+convert
  transpose_to_bf16<<<dim3(4096 / 32, 1024 / 32), 256, 0, stream>>>(in_proj_w, inT, 1024, 4096);
  transpose_to_bf16<<<dim3(256 / 32, 2048 / 32), 256, 0, stream>>>(B_proj_w, BCT, 2048, 256);
  transpose_to_bf16<<<dim3(256 / 32, 2048 / 32), 256, 0, stream>>>(C_proj_w, BCT + 256 * 2048, 2048, 256);
  dtT_kernel<<<128, 256, 0, stream>>>(dt_proj_w, BCT);
  transpose_to_bf16<<<dim3(1024 / 32, 2048 / 32), 256, 0, stream>>>(out_proj_w, opT, 2048, 1024);
  transpose_ilv16<<<dim3(4096 / 32, 1024 / 32), 256, 0, stream>>>(w1, w13T, 1024, 4096, 0);
  transpose_ilv16<<<dim3(4096 / 32, 1024 / 32), 256, 0, stream>>>(w3, w13T, 1024, 4096, 16);
  transpose_to_bf16<<<dim3(1024 / 32, 4096 / 32), 256, 0, stream>>>(w2, w2T, 4096, 1024);

  // 1) hb = rmsnorm(x)
  rmsnorm_bf16<<<BT, 256, 0, stream>>>(x, norm1_w, hb);
  // 2) uvb = hb @ in_proj  (512 blocks BN=256: all CUs, 1 round)
  gemm_pipe<1, 256><<<512, 512, 0, stream>>>(hb, inT, nullptr, uvb, BT, E2, DMODEL, 32, E2);
  // 3) vb = causal dwconv(uvb[:, E:2E])
  dwconv_bf16<<<dim3(EDIM / 256, BT), 256, 0, stream>>>(uvb, conv_w, vb);
  // 4) BCD = vb @ [B|C|dt] (N=640, store cols<528)
  gemm_pipe<0, 128><<<160, 256, 0, stream>>>(vb, BCT, nullptr, BCD, BT, 640, EDIM, 32, 528);
  // 5) chunked scan (softplus+bias inline) -> phase3 writes gated yg directly
  scan_phase1<<<NCH, 512, 0, stream>>>(BCD, A_log, dt_proj_b, Pc, Sc);
  scan_phase2<<<1, 512, 0, stream>>>(Pc, Sc, Init);
  scan_phase3<<<NCH, 512, 0, stream>>>(BCD, A_log, dt_proj_b, Init, uvb, yg);
  // 6) out = yg @ out_proj + x
  gemm_pipe<0, 128><<<256, 256, 0, stream>>>(yg, opT, x, out, BT, DMODEL, EDIM, 32, DMODEL);
  // 7) hb = rmsnorm(out)
  rmsnorm_bf16<<<BT, 256, 0, stream>>>(out, norm2_w, hb);
  // 8) ffb = swiglu(hb @ [w1|w3 ilv])  (1024 blocks BN=256)
  gemm_pipe<2, 256><<<1024, 512, 0, stream>>>(hb, w13T, nullptr, ffb, BT, 8192, DMODEL, 32, 8192);
  // 9) out += ffb @ w2
  gemm_pipe<0, 128><<<256, 256, 0, stream>>>(ffb, w2T, out, out, BT, DMODEL, DFF, 32, DMODEL);
}